// Round 7
// baseline (521.059 us; speedup 1.0000x reference)
//
#include <hip/hip_runtime.h>
#include <hip/hip_bf16.h>

#define N_NODES 50000
#define N_EDGES 500000
#define E2_EDGES 550000   // with self loops appended
#define F_IN 32
#define HEADS 4
#define CH 64
#define HC 256            // HEADS*CH
#define NB 1000
#define NHID 256
#define NOUT 256

static inline int cdiv(long long a, long long b) { return (int)((a + b - 1) / b); }

typedef __bf16 bf16x8 __attribute__((ext_vector_type(8)));
typedef unsigned short us8 __attribute__((ext_vector_type(8)));
typedef unsigned short us4 __attribute__((ext_vector_type(4)));
typedef float f32x4 __attribute__((ext_vector_type(4)));
union BU { us8 u; bf16x8 b; };

// round-to-nearest-even fp32 -> bf16 (bit pattern)
__device__ inline unsigned short f2bf(float f) {
    unsigned u = __float_as_uint(f);
    return (unsigned short)((u + 0x7fffu + ((u >> 16) & 1u)) >> 16);
}
__device__ inline float bf2f(unsigned short h) {
    return __uint_as_float(((unsigned)h) << 16);
}

// ---------- W prep: transpose + split fp32 -> (hi,lo) bf16 ----------
__global__ void wconv_kernel(const float* __restrict__ W,
                             unsigned short* __restrict__ Wt_hi,
                             unsigned short* __restrict__ Wt_lo, int K, int M) {
    int idx = blockIdx.x * blockDim.x + threadIdx.x;
    if (idx >= K * M) return;
    int k = idx / M, m = idx % M;
    float v = W[idx];
    unsigned short hi = f2bf(v);
    Wt_hi[(size_t)m * K + k] = hi;
    Wt_lo[(size_t)m * K + k] = f2bf(v - bf2f(hi));
}

// ---------- barrier-free register-direct split-bf16 MFMA GEMM ----------
// C[N,M] = A[N,K] @ W[K,M]. Wt_* are [M][K] (transposed, split hi/lo).
// No LDS, no __syncthreads: each wave owns 32 rows x WT cols; A and B
// fragments are loaded straight into registers (W is L2-resident), so
// loads of chunk k+1 overlap MFMAs of chunk k via plain vmcnt scheduling.
template<int K, int M, int WT, bool OBF>
__global__ __launch_bounds__(256) void mfma_lin_reg_kernel(
    const float* __restrict__ A, const unsigned short* __restrict__ Wt_hi,
    const unsigned short* __restrict__ Wt_lo, const float* __restrict__ bias,
    void* __restrict__ Cout, int n_rows) {
    constexpr int NT = WT / 16;     // col tiles per wave
    constexpr int NCH = K / 32;     // K chunks
    constexpr int CW = M / WT;      // col waves per block
    constexpr int RW = 4 / CW;      // row waves per block (block = RW*32 rows)
    const int wave = threadIdx.x >> 6, lane = threadIdx.x & 63;
    const int quad = lane >> 4, l16 = lane & 15;
    const int col0 = (wave % CW) * WT;
    const int row0 = blockIdx.x * (RW * 32) + (wave / CW) * 32;

    f32x4 acc[2][NT];
#pragma unroll
    for (int rs = 0; rs < 2; rs++)
#pragma unroll
        for (int t = 0; t < NT; t++) acc[rs][t] = (f32x4){0.f, 0.f, 0.f, 0.f};

    // clamped row indices for safe loads (stores are predicated)
    const int r0 = min(row0 + l16, n_rows - 1);
    const int r1 = min(row0 + 16 + l16, n_rows - 1);
    const float* a0p = A + (size_t)r0 * K + quad * 8;
    const float* a1p = A + (size_t)r1 * K + quad * 8;
    const unsigned short* bhp = Wt_hi + (size_t)(col0 + l16) * K + quad * 8;
    const unsigned short* blp = Wt_lo + (size_t)(col0 + l16) * K + quad * 8;

#pragma unroll
    for (int ch = 0; ch < NCH; ch++) {
        // ---- A fragments (2 rowsets), convert fp32 -> hi/lo bf16 in-reg ----
        BU ah[2], al[2];
        {
            float4 f0 = *(const float4*)(a0p + ch * 32);
            float4 f1 = *(const float4*)(a0p + ch * 32 + 4);
            float4 g0 = *(const float4*)(a1p + ch * 32);
            float4 g1 = *(const float4*)(a1p + ch * 32 + 4);
            float v0[8] = {f0.x, f0.y, f0.z, f0.w, f1.x, f1.y, f1.z, f1.w};
            float v1[8] = {g0.x, g0.y, g0.z, g0.w, g1.x, g1.y, g1.z, g1.w};
#pragma unroll
            for (int i = 0; i < 8; i++) {
                unsigned short h0 = f2bf(v0[i]);
                unsigned short h1 = f2bf(v1[i]);
                ah[0].u[i] = h0; al[0].u[i] = f2bf(v0[i] - bf2f(h0));
                ah[1].u[i] = h1; al[1].u[i] = f2bf(v1[i] - bf2f(h1));
            }
        }
        // ---- B fragments straight from L2, 3-term split MFMA ----
#pragma unroll
        for (int t = 0; t < NT; t++) {
            BU bh, bl;
            bh.u = *(const us8*)(bhp + (size_t)t * 16 * K + ch * 32);
            bl.u = *(const us8*)(blp + (size_t)t * 16 * K + ch * 32);
#pragma unroll
            for (int rs = 0; rs < 2; rs++) {
                acc[rs][t] = __builtin_amdgcn_mfma_f32_16x16x32_bf16(ah[rs].b, bh.b, acc[rs][t], 0, 0, 0);
                acc[rs][t] = __builtin_amdgcn_mfma_f32_16x16x32_bf16(ah[rs].b, bl.b, acc[rs][t], 0, 0, 0);
                acc[rs][t] = __builtin_amdgcn_mfma_f32_16x16x32_bf16(al[rs].b, bh.b, acc[rs][t], 0, 0, 0);
            }
        }
    }
    // ---- epilogue: row = row0 + rs*16 + quad*4 + i, col = col0 + t*16 + l16
#pragma unroll
    for (int rs = 0; rs < 2; rs++) {
        const int orow0 = row0 + rs * 16 + quad * 4;
#pragma unroll
        for (int t = 0; t < NT; t++) {
            float bv = bias ? bias[col0 + t * 16 + l16] : 0.f;
#pragma unroll
            for (int i = 0; i < 4; i++) {
                int r = orow0 + i;
                if (r < n_rows) {
                    float v = acc[rs][t][i] + bv;
                    if (OBF) ((unsigned short*)Cout)[(size_t)r * M + col0 + t * 16 + l16] = f2bf(v);
                    else     ((float*)Cout)[(size_t)r * M + col0 + t * 16 + l16] = v;
                }
            }
        }
    }
}

// ---------- generic small GEMM (MLP layer 1) ----------
template<int K, int M, int TM, int BLOCK, bool RELU>
__global__ __launch_bounds__(BLOCK) void lin_kernel(
    const float* __restrict__ A, const float* __restrict__ W,
    const float* __restrict__ bias, float* __restrict__ C, int n_rows) {
    __shared__ float As[TM][K];
    const int n0 = blockIdx.x * TM;
    const int tid = threadIdx.x;
    for (int idx = tid; idx < TM * K; idx += BLOCK) {
        int r = idx / K, c = idx % K;
        int n = n0 + r;
        As[r][c] = (n < n_rows) ? A[(size_t)n * K + c] : 0.f;
    }
    __syncthreads();
    constexpr int G = BLOCK / M;
    constexpr int RPT = TM / G;
    const int j = tid % M;
    const int g = tid / M;
    float acc[RPT];
#pragma unroll
    for (int i = 0; i < RPT; i++) acc[i] = 0.f;
    for (int k = 0; k < K; k++) {
        float wk = W[(size_t)k * M + j];
#pragma unroll
        for (int i = 0; i < RPT; i++) acc[i] += As[g * RPT + i][k] * wk;
    }
    float bv = bias ? bias[j] : 0.f;
#pragma unroll
    for (int i = 0; i < RPT; i++) {
        int n = n0 + g * RPT + i;
        if (n < n_rows) {
            float v = acc[i] + bv;
            if (RELU) v = fmaxf(v, 0.f);
            C[(size_t)n * M + j] = v;
        }
    }
}

// ---------- per-(node,head) attention logits from bf16 h ----------
template<int H_, int C_>
__global__ void attn_logits_kernel(const unsigned short* __restrict__ h,
                                   const float* __restrict__ a_src,
                                   const float* __restrict__ a_dst,
                                   float* __restrict__ als, float* __restrict__ ald,
                                   int n) {
    int t = blockIdx.x * blockDim.x + threadIdx.x;
    if (t >= n * H_) return;
    int node = t / H_, hh = t % H_;
    const us8* hp = (const us8*)(h + (size_t)node * (H_ * C_) + hh * C_);
    const float4* as = (const float4*)(a_src + hh * C_);
    const float4* ad = (const float4*)(a_dst + hh * C_);
    float ss = 0.f, sd = 0.f;
#pragma unroll
    for (int c = 0; c < C_ / 8; c++) {
        us8 hv = hp[c];
        float4 a0 = as[2 * c], a1 = as[2 * c + 1];
        float4 b0 = ad[2 * c], b1 = ad[2 * c + 1];
        float f0 = bf2f(hv[0]), f1 = bf2f(hv[1]), f2 = bf2f(hv[2]), f3 = bf2f(hv[3]);
        float f4 = bf2f(hv[4]), f5 = bf2f(hv[5]), f6 = bf2f(hv[6]), f7 = bf2f(hv[7]);
        ss += f0 * a0.x + f1 * a0.y + f2 * a0.z + f3 * a0.w
            + f4 * a1.x + f5 * a1.y + f6 * a1.z + f7 * a1.w;
        sd += f0 * b0.x + f1 * b0.y + f2 * b0.z + f3 * b0.w
            + f4 * b1.x + f5 * b1.y + f6 * b1.z + f7 * b1.w;
    }
    als[t] = ss;
    ald[t] = sd;
}

// ======================= CSR build =======================
__global__ void hist_kernel(const int* __restrict__ ei, int* __restrict__ deg) {
    int e = blockIdx.x * blockDim.x + threadIdx.x;
    if (e >= E2_EDGES) return;
    int d = (e < N_EDGES) ? ei[N_EDGES + e] : (e - N_EDGES);
    atomicAdd(deg + d, 1);
}

__global__ __launch_bounds__(256) void scan_block_kernel(const int* __restrict__ deg,
                                                         int* __restrict__ rowptr,
                                                         int* __restrict__ bsum) {
    __shared__ int sdata[256];
    const int b = blockIdx.x, t = threadIdx.x;
    const int base = b * 1024 + t * 4;
    int v[4]; int s = 0;
#pragma unroll
    for (int i = 0; i < 4; i++) {
        int idx = base + i;
        v[i] = (idx < N_NODES) ? deg[idx] : 0;
        s += v[i];
    }
    sdata[t] = s;
    __syncthreads();
    for (int o = 1; o < 256; o <<= 1) {
        int x = (t >= o) ? sdata[t - o] : 0;
        __syncthreads();
        sdata[t] += x;
        __syncthreads();
    }
    if (t == 255) bsum[b] = sdata[255];
    int run = sdata[t] - s;
#pragma unroll
    for (int i = 0; i < 4; i++) {
        int idx = base + i;
        if (idx < N_NODES) rowptr[idx] = run;
        run += v[i];
    }
}

__global__ void scan_bsum_kernel(int* __restrict__ bsum, int nb) {
    if (threadIdx.x == 0 && blockIdx.x == 0) {
        int run = 0;
        for (int i = 0; i < nb; i++) { int v = bsum[i]; bsum[i] = run; run += v; }
    }
}

__global__ void finalize_rowptr_kernel(int* __restrict__ rowptr, const int* __restrict__ bsum,
                                       int* __restrict__ cursor) {
    int i = blockIdx.x * blockDim.x + threadIdx.x;
    if (i >= N_NODES) return;
    int v = rowptr[i] + bsum[i >> 10];
    rowptr[i] = v;
    cursor[i] = v;
}

__global__ void scatter_kernel(const int* __restrict__ ei, int* __restrict__ cursor,
                               int* __restrict__ csr_src) {
    int e = blockIdx.x * blockDim.x + threadIdx.x;
    if (e >= E2_EDGES) return;
    int s, d;
    if (e < N_EDGES) { s = ei[e]; d = ei[N_EDGES + e]; }
    else             { s = d = e - N_EDGES; }
    int pos = atomicAdd(cursor + d, 1);
    csr_src[pos] = s;
}

// ======================= wide GAT agg: 1 wave/node, lane owns 4 ch (bf16 h) ==
template<bool RELU>
__global__ __launch_bounds__(256) void gat_agg_wide_kernel(
    const int* __restrict__ csr_src, const int* __restrict__ rowptr,
    const int* __restrict__ deg, const unsigned short* __restrict__ h,
    const float* __restrict__ als, const float* __restrict__ ald,
    const float* __restrict__ bias, float* __restrict__ out, int n) {
    const int lane = threadIdx.x & 63;
    const int node = (blockIdx.x << 2) + (threadIdx.x >> 6);
    if (node >= n) return;
    const int hh = lane >> 4;
    const int start = rowptr[node];
    const int len = deg[node];
    const float ad = ald[(node << 2) + hh];
    float m = -1e30f, z = 0.f;
    float4 acc = make_float4(0.f, 0.f, 0.f, 0.f);
    int k = 0;
    for (; k + 4 <= len; k += 4) {
        int s0 = csr_src[start + k + 0];
        int s1 = csr_src[start + k + 1];
        int s2 = csr_src[start + k + 2];
        int s3 = csr_src[start + k + 3];
        float a0 = als[(s0 << 2) + hh], a1 = als[(s1 << 2) + hh];
        float a2 = als[(s2 << 2) + hh], a3 = als[(s3 << 2) + hh];
        us4 h0 = *(const us4*)(h + ((size_t)s0 << 8) + (lane << 2));
        us4 h1 = *(const us4*)(h + ((size_t)s1 << 8) + (lane << 2));
        us4 h2 = *(const us4*)(h + ((size_t)s2 << 8) + (lane << 2));
        us4 h3 = *(const us4*)(h + ((size_t)s3 << 8) + (lane << 2));
        float x0 = a0 + ad; x0 = (x0 > 0.f) ? x0 : 0.2f * x0;
        float x1 = a1 + ad; x1 = (x1 > 0.f) ? x1 : 0.2f * x1;
        float x2 = a2 + ad; x2 = (x2 > 0.f) ? x2 : 0.2f * x2;
        float x3 = a3 + ad; x3 = (x3 > 0.f) ? x3 : 0.2f * x3;
        float nm = fmaxf(fmaxf(fmaxf(x0, x1), fmaxf(x2, x3)), m);
        float c  = __expf(m - nm);
        float p0 = __expf(x0 - nm), p1 = __expf(x1 - nm);
        float p2 = __expf(x2 - nm), p3 = __expf(x3 - nm);
        m = nm;
        z = z * c + p0 + p1 + p2 + p3;
        acc.x = acc.x * c + p0 * bf2f(h0[0]) + p1 * bf2f(h1[0]) + p2 * bf2f(h2[0]) + p3 * bf2f(h3[0]);
        acc.y = acc.y * c + p0 * bf2f(h0[1]) + p1 * bf2f(h1[1]) + p2 * bf2f(h2[1]) + p3 * bf2f(h3[1]);
        acc.z = acc.z * c + p0 * bf2f(h0[2]) + p1 * bf2f(h1[2]) + p2 * bf2f(h2[2]) + p3 * bf2f(h3[2]);
        acc.w = acc.w * c + p0 * bf2f(h0[3]) + p1 * bf2f(h1[3]) + p2 * bf2f(h2[3]) + p3 * bf2f(h3[3]);
    }
    for (; k < len; k++) {
        int s0 = csr_src[start + k];
        float x0 = als[(s0 << 2) + hh] + ad; x0 = (x0 > 0.f) ? x0 : 0.2f * x0;
        us4 h0 = *(const us4*)(h + ((size_t)s0 << 8) + (lane << 2));
        float nm = fmaxf(m, x0);
        float c  = __expf(m - nm);
        float p0 = __expf(x0 - nm);
        m = nm;
        z = z * c + p0;
        acc.x = acc.x * c + p0 * bf2f(h0[0]);
        acc.y = acc.y * c + p0 * bf2f(h0[1]);
        acc.z = acc.z * c + p0 * bf2f(h0[2]);
        acc.w = acc.w * c + p0 * bf2f(h0[3]);
    }
    float inv = 1.f / (z + 1e-16f);
    float4 bv = *(const float4*)(bias + (lane << 2));
    float4 v;
    v.x = acc.x * inv + bv.x;
    v.y = acc.y * inv + bv.y;
    v.z = acc.z * inv + bv.z;
    v.w = acc.w * inv + bv.w;
    if (RELU) {
        v.x = fmaxf(v.x, 0.f); v.y = fmaxf(v.y, 0.f);
        v.z = fmaxf(v.z, 0.f); v.w = fmaxf(v.w, 0.f);
    }
    *(float4*)(out + ((size_t)node << 8) + (lane << 2)) = v;
}

// ======================= layer-3 agg: H=1, C=64 (bf16 h) ======
__global__ __launch_bounds__(256) void gat_agg_h1_kernel(
    const int* __restrict__ csr_src, const int* __restrict__ rowptr,
    const int* __restrict__ deg, const unsigned short* __restrict__ h,
    const float* __restrict__ als, const float* __restrict__ ald,
    const float* __restrict__ bias, float* __restrict__ out, int n) {
    const int lane = threadIdx.x & 63;
    const int node = (blockIdx.x << 2) + (threadIdx.x >> 6);
    if (node >= n) return;
    const int start = rowptr[node];
    const int len = deg[node];
    const float ad = ald[node];
    float m = -1e30f, z = 0.f, acc = 0.f;
    int k = 0;
    for (; k + 4 <= len; k += 4) {
        int s0 = csr_src[start + k + 0];
        int s1 = csr_src[start + k + 1];
        int s2 = csr_src[start + k + 2];
        int s3 = csr_src[start + k + 3];
        float a0 = als[s0], a1 = als[s1], a2 = als[s2], a3 = als[s3];
        float h0 = bf2f(h[((size_t)s0 << 6) + lane]);
        float h1 = bf2f(h[((size_t)s1 << 6) + lane]);
        float h2 = bf2f(h[((size_t)s2 << 6) + lane]);
        float h3 = bf2f(h[((size_t)s3 << 6) + lane]);
        float x0 = a0 + ad; x0 = (x0 > 0.f) ? x0 : 0.2f * x0;
        float x1 = a1 + ad; x1 = (x1 > 0.f) ? x1 : 0.2f * x1;
        float x2 = a2 + ad; x2 = (x2 > 0.f) ? x2 : 0.2f * x2;
        float x3 = a3 + ad; x3 = (x3 > 0.f) ? x3 : 0.2f * x3;
        float nm = fmaxf(fmaxf(fmaxf(x0, x1), fmaxf(x2, x3)), m);
        float c  = __expf(m - nm);
        float p0 = __expf(x0 - nm), p1 = __expf(x1 - nm);
        float p2 = __expf(x2 - nm), p3 = __expf(x3 - nm);
        m = nm;
        z = z * c + p0 + p1 + p2 + p3;
        acc = acc * c + p0 * h0 + p1 * h1 + p2 * h2 + p3 * h3;
    }
    for (; k < len; k++) {
        int s0 = csr_src[start + k];
        float x0 = als[s0] + ad; x0 = (x0 > 0.f) ? x0 : 0.2f * x0;
        float h0 = bf2f(h[((size_t)s0 << 6) + lane]);
        float nm = fmaxf(m, x0);
        float c  = __expf(m - nm);
        float p0 = __expf(x0 - nm);
        m = nm;
        z = z * c + p0;
        acc = acc * c + p0 * h0;
    }
    out[((size_t)node << 6) + lane] = acc / (z + 1e-16f) + bias[lane];
}

// ---------- mean pooling over (sorted) batch via binary search ----------
__global__ __launch_bounds__(64) void pool_kernel(const float* __restrict__ h3,
                                                  const int* __restrict__ batch,
                                                  float* __restrict__ xg) {
    const int b = blockIdx.x;
    const int j = threadIdx.x;
    int lo = 0, hi = N_NODES;
    while (lo < hi) { int mid = (lo + hi) >> 1; if (batch[mid] < b) lo = mid + 1; else hi = mid; }
    const int start = lo;
    hi = N_NODES;
    while (lo < hi) { int mid = (lo + hi) >> 1; if (batch[mid] < b + 1) lo = mid + 1; else hi = mid; }
    const int end = lo;
    float s = 0.f;
    for (int n = start; n < end; n++) s += h3[(size_t)n * CH + j];
    xg[b * CH + j] = s / fmaxf((float)(end - start), 1.f);
}

// ---------- MLP layer 2 + LayerNorm, one block per graph ----------
__global__ __launch_bounds__(256) void mlp2_ln_kernel(
    const float* __restrict__ y1, const float* __restrict__ Wm2,
    const float* __restrict__ bm2, const float* __restrict__ g2,
    const float* __restrict__ be2, float* __restrict__ out) {
    const int b = blockIdx.x;
    const int j = threadIdx.x;
    __shared__ float yr[NHID];
    yr[j] = y1[(size_t)b * NHID + j];
    __syncthreads();
    float acc = bm2[j];
#pragma unroll 8
    for (int k = 0; k < NHID; k++) acc += yr[k] * Wm2[(size_t)k * NOUT + j];
    float s = acc, s2 = acc * acc;
    for (int o = 32; o > 0; o >>= 1) {
        s += __shfl_down(s, o);
        s2 += __shfl_down(s2, o);
    }
    __shared__ float red[8];
    __shared__ float mv[2];
    int wave = j >> 6, lane = j & 63;
    if (lane == 0) { red[wave] = s; red[4 + wave] = s2; }
    __syncthreads();
    if (j == 0) {
        float ts = red[0] + red[1] + red[2] + red[3];
        float ts2 = red[4] + red[5] + red[6] + red[7];
        float mu = ts / (float)NOUT;
        float var = ts2 / (float)NOUT - mu * mu;
        mv[0] = mu;
        mv[1] = rsqrtf(var + 1e-5f);
    }
    __syncthreads();
    out[(size_t)b * NOUT + j] = (acc - mv[0]) * mv[1] * g2[j] + be2[j];
}

extern "C" void kernel_launch(void* const* d_in, const int* in_sizes, int n_in,
                              void* d_out, int out_size, void* d_ws, size_t ws_size,
                              hipStream_t stream) {
    const float* x      = (const float*)d_in[0];
    const int*   ei     = (const int*)d_in[1];
    const int*   batch  = (const int*)d_in[2];
    const float* W1     = (const float*)d_in[3];
    const float* as1    = (const float*)d_in[4];
    const float* ad1    = (const float*)d_in[5];
    const float* b1     = (const float*)d_in[6];
    const float* W2     = (const float*)d_in[7];
    const float* as2    = (const float*)d_in[8];
    const float* ad2    = (const float*)d_in[9];
    const float* b2     = (const float*)d_in[10];
    const float* W3     = (const float*)d_in[11];
    const float* as3    = (const float*)d_in[12];
    const float* ad3    = (const float*)d_in[13];
    const float* b3     = (const float*)d_in[14];
    const float* Wm1    = (const float*)d_in[15];
    const float* bm1    = (const float*)d_in[16];
    const float* Wm2    = (const float*)d_in[17];
    const float* bm2    = (const float*)d_in[18];
    const float* g2     = (const float*)d_in[19];
    const float* be2    = (const float*)d_in[20];
    float* out = (float*)d_out;

    // workspace layout
    float* bufO = (float*)d_ws;                              // N*HC fp32
    float* als  = bufO + (size_t)N_NODES * HC;               // N*HEADS
    float* ald  = als + (size_t)N_NODES * HEADS;             // N*HEADS
    float* xg   = ald + (size_t)N_NODES * HEADS;             // NB*CH
    float* y1   = xg + (size_t)NB * CH;                      // NB*NHID
    unsigned short* bufH = (unsigned short*)(y1 + (size_t)NB * NHID);  // N*HC bf16
    int* deg     = (int*)(bufH + (size_t)N_NODES * HC);      // N
    int* rowptr  = deg + N_NODES;                            // N
    int* cursor  = rowptr + N_NODES;                         // N
    int* bsum    = cursor + N_NODES;                         // <=64
    int* csr_src = bsum + 64;                                // E2
    unsigned short* wt1h = (unsigned short*)(csr_src + E2_EDGES);  // 256*32
    unsigned short* wt1l = wt1h + 256 * 32;
    unsigned short* wt2h = wt1l + 256 * 32;                        // 256*256
    unsigned short* wt2l = wt2h + 256 * 256;
    unsigned short* wt3h = wt2l + 256 * 256;                       // 64*256
    unsigned short* wt3l = wt3h + 64 * 256;

    const int BLK = 256;
    const int NSCAN = cdiv(N_NODES, 1024);

    // ===================== weight prep (split bf16, transposed) ==============
    wconv_kernel<<<cdiv(F_IN * HC, BLK), BLK, 0, stream>>>(W1, wt1h, wt1l, F_IN, HC);
    wconv_kernel<<<cdiv(HC * HC, BLK), BLK, 0, stream>>>(W2, wt2h, wt2l, HC, HC);
    wconv_kernel<<<cdiv(HC * CH, BLK), BLK, 0, stream>>>(W3, wt3h, wt3l, HC, CH);

    // ===================== CSR build (dst-sorted adjacency) ==================
    hipMemsetAsync(deg, 0, (size_t)N_NODES * sizeof(int), stream);
    hist_kernel<<<cdiv(E2_EDGES, BLK), BLK, 0, stream>>>(ei, deg);
    scan_block_kernel<<<NSCAN, 256, 0, stream>>>(deg, rowptr, bsum);
    scan_bsum_kernel<<<1, 64, 0, stream>>>(bsum, NSCAN);
    finalize_rowptr_kernel<<<cdiv(N_NODES, BLK), BLK, 0, stream>>>(rowptr, bsum, cursor);
    scatter_kernel<<<cdiv(E2_EDGES, BLK), BLK, 0, stream>>>(ei, cursor, csr_src);

    // ===================== Layer 1 (F_IN -> H*C) =====================
    mfma_lin_reg_kernel<F_IN, HC, 128, true><<<cdiv(N_NODES, 64), 256, 0, stream>>>(
        x, wt1h, wt1l, nullptr, bufH, N_NODES);
    attn_logits_kernel<HEADS, CH><<<cdiv((long long)N_NODES * HEADS, BLK), BLK, 0, stream>>>(
        bufH, as1, ad1, als, ald, N_NODES);
    gat_agg_wide_kernel<true><<<cdiv(N_NODES, 4), 256, 0, stream>>>(
        csr_src, rowptr, deg, bufH, als, ald, b1, bufO, N_NODES);

    // ===================== Layer 2 (H*C -> H*C) =====================
    mfma_lin_reg_kernel<HC, HC, 128, true><<<cdiv(N_NODES, 64), 256, 0, stream>>>(
        bufO, wt2h, wt2l, nullptr, bufH, N_NODES);
    attn_logits_kernel<HEADS, CH><<<cdiv((long long)N_NODES * HEADS, BLK), BLK, 0, stream>>>(
        bufH, as2, ad2, als, ald, N_NODES);
    gat_agg_wide_kernel<true><<<cdiv(N_NODES, 4), 256, 0, stream>>>(
        csr_src, rowptr, deg, bufH, als, ald, b2, bufO, N_NODES);

    // ===================== Layer 3 (H*C -> C, heads=1) =====================
    mfma_lin_reg_kernel<HC, CH, 64, true><<<cdiv(N_NODES, 128), 256, 0, stream>>>(
        bufO, wt3h, wt3l, nullptr, bufH, N_NODES);
    attn_logits_kernel<1, CH><<<cdiv(N_NODES, BLK), BLK, 0, stream>>>(
        bufH, as3, ad3, als, ald, N_NODES);
    gat_agg_h1_kernel<<<cdiv(N_NODES, 4), 256, 0, stream>>>(
        csr_src, rowptr, deg, bufH, als, ald, b3, bufO, N_NODES);

    // ===================== Mean pooling (batch is sorted) =====================
    pool_kernel<<<NB, 64, 0, stream>>>(bufO, batch, xg);

    // ===================== MLP head + LayerNorm =====================
    lin_kernel<CH, NHID, 16, 256, true><<<cdiv(NB, 16), 256, 0, stream>>>(
        xg, Wm1, bm1, y1, NB);
    mlp2_ln_kernel<<<NB, 256, 0, stream>>>(y1, Wm2, bm2, g2, be2, out);
}

// Round 8
// 483.720 us; speedup vs baseline: 1.0772x; 1.0772x over previous
//
#include <hip/hip_runtime.h>
#include <hip/hip_bf16.h>

#define N_NODES 50000
#define N_EDGES 500000
#define E2_EDGES 550000   // with self loops appended
#define F_IN 32
#define HEADS 4
#define CH 64
#define HC 256            // HEADS*CH
#define NB 1000
#define NHID 256
#define NOUT 256

static inline int cdiv(long long a, long long b) { return (int)((a + b - 1) / b); }

typedef __bf16 bf16x8 __attribute__((ext_vector_type(8)));
typedef unsigned short us8 __attribute__((ext_vector_type(8)));
typedef unsigned short us4 __attribute__((ext_vector_type(4)));
typedef float f32x4 __attribute__((ext_vector_type(4)));
union BU { us8 u; bf16x8 b; };

// round-to-nearest-even fp32 -> bf16 (bit pattern)
__device__ inline unsigned short f2bf(float f) {
    unsigned u = __float_as_uint(f);
    return (unsigned short)((u + 0x7fffu + ((u >> 16) & 1u)) >> 16);
}
__device__ inline float bf2f(unsigned short h) {
    return __uint_as_float(((unsigned)h) << 16);
}

// ---------- W prep: split fp32 -> (hi,lo) bf16 in MFMA-fragment-major order --
// Wf[(tcol*NCH + ch)*64*8 + lane*8 + j] where lane=quad*16+l16 holds
// W[ch*32+quad*8+j][tcol*16+l16]. A wave's B-fragment load is then
// base + lane*16B -> one coalesced 1KB transaction (fixes R7's 512B-stride
// scatter that regressed the register-direct GEMM).
__global__ void wconv_frag_kernel(const float* __restrict__ W,
                                  unsigned short* __restrict__ Wf_hi,
                                  unsigned short* __restrict__ Wf_lo, int K, int M) {
    int idx = blockIdx.x * blockDim.x + threadIdx.x;
    if (idx >= K * M) return;
    int k = idx / M, m = idx % M;
    float v = W[idx];
    unsigned short hi = f2bf(v);
    unsigned short lo = f2bf(v - bf2f(hi));
    int tcol = m >> 4, l16 = m & 15;
    int ch = k >> 5, quad = (k >> 3) & 3, j = k & 7;
    int NCH = K >> 5;
    size_t dst = ((((size_t)tcol * NCH + ch) * 64) + quad * 16 + l16) * 8 + j;
    Wf_hi[dst] = hi;
    Wf_lo[dst] = lo;
}

// ---------- barrier-free register-direct split-bf16 MFMA GEMM ----------
// C[N,M] = A[N,K] @ W[K,M]. Wf_* in fragment-major order (see wconv_frag).
// No LDS, no __syncthreads; wave owns 32 rows x WT cols.
template<int K, int M, int WT, bool OBF>
__global__ __launch_bounds__(256) void mfma_lin_reg_kernel(
    const float* __restrict__ A, const unsigned short* __restrict__ Wf_hi,
    const unsigned short* __restrict__ Wf_lo, const float* __restrict__ bias,
    void* __restrict__ Cout, int n_rows) {
    constexpr int NT = WT / 16;     // col tiles per wave
    constexpr int NCH = K / 32;     // K chunks
    constexpr int CW = M / WT;      // col waves per block
    constexpr int RW = 4 / CW;      // row waves per block
    const int wave = threadIdx.x >> 6, lane = threadIdx.x & 63;
    const int quad = lane >> 4, l16 = lane & 15;
    const int col0 = (wave % CW) * WT;
    const int row0 = blockIdx.x * (RW * 32) + (wave / CW) * 32;

    f32x4 acc[2][NT];
#pragma unroll
    for (int rs = 0; rs < 2; rs++)
#pragma unroll
        for (int t = 0; t < NT; t++) acc[rs][t] = (f32x4){0.f, 0.f, 0.f, 0.f};

    // clamped row indices for safe loads (stores are predicated)
    const int r0 = min(row0 + l16, n_rows - 1);
    const int r1 = min(row0 + 16 + l16, n_rows - 1);
    const float* a0p = A + (size_t)r0 * K + quad * 8;
    const float* a1p = A + (size_t)r1 * K + quad * 8;
    // fragment-major B base: this wave starts at column tile col0/16
    const unsigned short* bh = Wf_hi + ((size_t)(col0 >> 4) * NCH * 64 + lane) * 8;
    const unsigned short* bl = Wf_lo + ((size_t)(col0 >> 4) * NCH * 64 + lane) * 8;

#pragma unroll
    for (int ch = 0; ch < NCH; ch++) {
        // ---- A fragments (2 rowsets), convert fp32 -> hi/lo bf16 in-reg ----
        BU ah[2], al[2];
        {
            float4 f0 = *(const float4*)(a0p + ch * 32);
            float4 f1 = *(const float4*)(a0p + ch * 32 + 4);
            float4 g0 = *(const float4*)(a1p + ch * 32);
            float4 g1 = *(const float4*)(a1p + ch * 32 + 4);
            float v0[8] = {f0.x, f0.y, f0.z, f0.w, f1.x, f1.y, f1.z, f1.w};
            float v1[8] = {g0.x, g0.y, g0.z, g0.w, g1.x, g1.y, g1.z, g1.w};
#pragma unroll
            for (int i = 0; i < 8; i++) {
                unsigned short h0 = f2bf(v0[i]);
                unsigned short h1 = f2bf(v1[i]);
                ah[0].u[i] = h0; al[0].u[i] = f2bf(v0[i] - bf2f(h0));
                ah[1].u[i] = h1; al[1].u[i] = f2bf(v1[i] - bf2f(h1));
            }
        }
        // ---- B fragments: coalesced 1KB loads, 3-term split MFMA ----
#pragma unroll
        for (int t = 0; t < NT; t++) {
            BU bhf, blf;
            bhf.u = *(const us8*)(bh + (size_t)(t * NCH + ch) * 64 * 8);
            blf.u = *(const us8*)(bl + (size_t)(t * NCH + ch) * 64 * 8);
#pragma unroll
            for (int rs = 0; rs < 2; rs++) {
                acc[rs][t] = __builtin_amdgcn_mfma_f32_16x16x32_bf16(ah[rs].b, bhf.b, acc[rs][t], 0, 0, 0);
                acc[rs][t] = __builtin_amdgcn_mfma_f32_16x16x32_bf16(ah[rs].b, blf.b, acc[rs][t], 0, 0, 0);
                acc[rs][t] = __builtin_amdgcn_mfma_f32_16x16x32_bf16(al[rs].b, bhf.b, acc[rs][t], 0, 0, 0);
            }
        }
    }
    // ---- epilogue: row = row0 + rs*16 + quad*4 + i, col = col0 + t*16 + l16
#pragma unroll
    for (int rs = 0; rs < 2; rs++) {
        const int orow0 = row0 + rs * 16 + quad * 4;
#pragma unroll
        for (int t = 0; t < NT; t++) {
            float bv = bias ? bias[col0 + t * 16 + l16] : 0.f;
#pragma unroll
            for (int i = 0; i < 4; i++) {
                int r = orow0 + i;
                if (r < n_rows) {
                    float v = acc[rs][t][i] + bv;
                    if (OBF) ((unsigned short*)Cout)[(size_t)r * M + col0 + t * 16 + l16] = f2bf(v);
                    else     ((float*)Cout)[(size_t)r * M + col0 + t * 16 + l16] = v;
                }
            }
        }
    }
}

// ---------- generic small GEMM (MLP layer 1) ----------
template<int K, int M, int TM, int BLOCK, bool RELU>
__global__ __launch_bounds__(BLOCK) void lin_kernel(
    const float* __restrict__ A, const float* __restrict__ W,
    const float* __restrict__ bias, float* __restrict__ C, int n_rows) {
    __shared__ float As[TM][K];
    const int n0 = blockIdx.x * TM;
    const int tid = threadIdx.x;
    for (int idx = tid; idx < TM * K; idx += BLOCK) {
        int r = idx / K, c = idx % K;
        int n = n0 + r;
        As[r][c] = (n < n_rows) ? A[(size_t)n * K + c] : 0.f;
    }
    __syncthreads();
    constexpr int G = BLOCK / M;
    constexpr int RPT = TM / G;
    const int j = tid % M;
    const int g = tid / M;
    float acc[RPT];
#pragma unroll
    for (int i = 0; i < RPT; i++) acc[i] = 0.f;
    for (int k = 0; k < K; k++) {
        float wk = W[(size_t)k * M + j];
#pragma unroll
        for (int i = 0; i < RPT; i++) acc[i] += As[g * RPT + i][k] * wk;
    }
    float bv = bias ? bias[j] : 0.f;
#pragma unroll
    for (int i = 0; i < RPT; i++) {
        int n = n0 + g * RPT + i;
        if (n < n_rows) {
            float v = acc[i] + bv;
            if (RELU) v = fmaxf(v, 0.f);
            C[(size_t)n * M + j] = v;
        }
    }
}

// ---------- per-(node,head) attention logits from bf16 h ----------
template<int H_, int C_>
__global__ void attn_logits_kernel(const unsigned short* __restrict__ h,
                                   const float* __restrict__ a_src,
                                   const float* __restrict__ a_dst,
                                   float* __restrict__ als, float* __restrict__ ald,
                                   int n) {
    int t = blockIdx.x * blockDim.x + threadIdx.x;
    if (t >= n * H_) return;
    int node = t / H_, hh = t % H_;
    const us8* hp = (const us8*)(h + (size_t)node * (H_ * C_) + hh * C_);
    const float4* as = (const float4*)(a_src + hh * C_);
    const float4* ad = (const float4*)(a_dst + hh * C_);
    float ss = 0.f, sd = 0.f;
#pragma unroll
    for (int c = 0; c < C_ / 8; c++) {
        us8 hv = hp[c];
        float4 a0 = as[2 * c], a1 = as[2 * c + 1];
        float4 b0 = ad[2 * c], b1 = ad[2 * c + 1];
        float f0 = bf2f(hv[0]), f1 = bf2f(hv[1]), f2 = bf2f(hv[2]), f3 = bf2f(hv[3]);
        float f4 = bf2f(hv[4]), f5 = bf2f(hv[5]), f6 = bf2f(hv[6]), f7 = bf2f(hv[7]);
        ss += f0 * a0.x + f1 * a0.y + f2 * a0.z + f3 * a0.w
            + f4 * a1.x + f5 * a1.y + f6 * a1.z + f7 * a1.w;
        sd += f0 * b0.x + f1 * b0.y + f2 * b0.z + f3 * b0.w
            + f4 * b1.x + f5 * b1.y + f6 * b1.z + f7 * b1.w;
    }
    als[t] = ss;
    ald[t] = sd;
}

// ======================= CSR build =======================
__global__ void hist_kernel(const int* __restrict__ ei, int* __restrict__ deg) {
    int e = blockIdx.x * blockDim.x + threadIdx.x;
    if (e >= E2_EDGES) return;
    int d = (e < N_EDGES) ? ei[N_EDGES + e] : (e - N_EDGES);
    atomicAdd(deg + d, 1);
}

__global__ __launch_bounds__(256) void scan_block_kernel(const int* __restrict__ deg,
                                                         int* __restrict__ rowptr,
                                                         int* __restrict__ bsum) {
    __shared__ int sdata[256];
    const int b = blockIdx.x, t = threadIdx.x;
    const int base = b * 1024 + t * 4;
    int v[4]; int s = 0;
#pragma unroll
    for (int i = 0; i < 4; i++) {
        int idx = base + i;
        v[i] = (idx < N_NODES) ? deg[idx] : 0;
        s += v[i];
    }
    sdata[t] = s;
    __syncthreads();
    for (int o = 1; o < 256; o <<= 1) {
        int x = (t >= o) ? sdata[t - o] : 0;
        __syncthreads();
        sdata[t] += x;
        __syncthreads();
    }
    if (t == 255) bsum[b] = sdata[255];
    int run = sdata[t] - s;
#pragma unroll
    for (int i = 0; i < 4; i++) {
        int idx = base + i;
        if (idx < N_NODES) rowptr[idx] = run;
        run += v[i];
    }
}

__global__ void scan_bsum_kernel(int* __restrict__ bsum, int nb) {
    if (threadIdx.x == 0 && blockIdx.x == 0) {
        int run = 0;
        for (int i = 0; i < nb; i++) { int v = bsum[i]; bsum[i] = run; run += v; }
    }
}

__global__ void finalize_rowptr_kernel(int* __restrict__ rowptr, const int* __restrict__ bsum,
                                       int* __restrict__ cursor) {
    int i = blockIdx.x * blockDim.x + threadIdx.x;
    if (i >= N_NODES) return;
    int v = rowptr[i] + bsum[i >> 10];
    rowptr[i] = v;
    cursor[i] = v;
}

__global__ void scatter_kernel(const int* __restrict__ ei, int* __restrict__ cursor,
                               int* __restrict__ csr_src) {
    int e = blockIdx.x * blockDim.x + threadIdx.x;
    if (e >= E2_EDGES) return;
    int s, d;
    if (e < N_EDGES) { s = ei[e]; d = ei[N_EDGES + e]; }
    else             { s = d = e - N_EDGES; }
    int pos = atomicAdd(cursor + d, 1);
    csr_src[pos] = s;
}

// ======================= wide GAT agg: 1 wave/node, lane owns 4 ch (bf16 h) ==
template<bool RELU>
__global__ __launch_bounds__(256) void gat_agg_wide_kernel(
    const int* __restrict__ csr_src, const int* __restrict__ rowptr,
    const int* __restrict__ deg, const unsigned short* __restrict__ h,
    const float* __restrict__ als, const float* __restrict__ ald,
    const float* __restrict__ bias, float* __restrict__ out, int n) {
    const int lane = threadIdx.x & 63;
    const int node = (blockIdx.x << 2) + (threadIdx.x >> 6);
    if (node >= n) return;
    const int hh = lane >> 4;
    const int start = rowptr[node];
    const int len = deg[node];
    const float ad = ald[(node << 2) + hh];
    float m = -1e30f, z = 0.f;
    float4 acc = make_float4(0.f, 0.f, 0.f, 0.f);
    int k = 0;
    for (; k + 4 <= len; k += 4) {
        int s0 = csr_src[start + k + 0];
        int s1 = csr_src[start + k + 1];
        int s2 = csr_src[start + k + 2];
        int s3 = csr_src[start + k + 3];
        float a0 = als[(s0 << 2) + hh], a1 = als[(s1 << 2) + hh];
        float a2 = als[(s2 << 2) + hh], a3 = als[(s3 << 2) + hh];
        us4 h0 = *(const us4*)(h + ((size_t)s0 << 8) + (lane << 2));
        us4 h1 = *(const us4*)(h + ((size_t)s1 << 8) + (lane << 2));
        us4 h2 = *(const us4*)(h + ((size_t)s2 << 8) + (lane << 2));
        us4 h3 = *(const us4*)(h + ((size_t)s3 << 8) + (lane << 2));
        float x0 = a0 + ad; x0 = (x0 > 0.f) ? x0 : 0.2f * x0;
        float x1 = a1 + ad; x1 = (x1 > 0.f) ? x1 : 0.2f * x1;
        float x2 = a2 + ad; x2 = (x2 > 0.f) ? x2 : 0.2f * x2;
        float x3 = a3 + ad; x3 = (x3 > 0.f) ? x3 : 0.2f * x3;
        float nm = fmaxf(fmaxf(fmaxf(x0, x1), fmaxf(x2, x3)), m);
        float c  = __expf(m - nm);
        float p0 = __expf(x0 - nm), p1 = __expf(x1 - nm);
        float p2 = __expf(x2 - nm), p3 = __expf(x3 - nm);
        m = nm;
        z = z * c + p0 + p1 + p2 + p3;
        acc.x = acc.x * c + p0 * bf2f(h0[0]) + p1 * bf2f(h1[0]) + p2 * bf2f(h2[0]) + p3 * bf2f(h3[0]);
        acc.y = acc.y * c + p0 * bf2f(h0[1]) + p1 * bf2f(h1[1]) + p2 * bf2f(h2[1]) + p3 * bf2f(h3[1]);
        acc.z = acc.z * c + p0 * bf2f(h0[2]) + p1 * bf2f(h1[2]) + p2 * bf2f(h2[2]) + p3 * bf2f(h3[2]);
        acc.w = acc.w * c + p0 * bf2f(h0[3]) + p1 * bf2f(h1[3]) + p2 * bf2f(h2[3]) + p3 * bf2f(h3[3]);
    }
    for (; k < len; k++) {
        int s0 = csr_src[start + k];
        float x0 = als[(s0 << 2) + hh] + ad; x0 = (x0 > 0.f) ? x0 : 0.2f * x0;
        us4 h0 = *(const us4*)(h + ((size_t)s0 << 8) + (lane << 2));
        float nm = fmaxf(m, x0);
        float c  = __expf(m - nm);
        float p0 = __expf(x0 - nm);
        m = nm;
        z = z * c + p0;
        acc.x = acc.x * c + p0 * bf2f(h0[0]);
        acc.y = acc.y * c + p0 * bf2f(h0[1]);
        acc.z = acc.z * c + p0 * bf2f(h0[2]);
        acc.w = acc.w * c + p0 * bf2f(h0[3]);
    }
    float inv = 1.f / (z + 1e-16f);
    float4 bv = *(const float4*)(bias + (lane << 2));
    float4 v;
    v.x = acc.x * inv + bv.x;
    v.y = acc.y * inv + bv.y;
    v.z = acc.z * inv + bv.z;
    v.w = acc.w * inv + bv.w;
    if (RELU) {
        v.x = fmaxf(v.x, 0.f); v.y = fmaxf(v.y, 0.f);
        v.z = fmaxf(v.z, 0.f); v.w = fmaxf(v.w, 0.f);
    }
    *(float4*)(out + ((size_t)node << 8) + (lane << 2)) = v;
}

// ======================= layer-3 agg: H=1, C=64 (bf16 h) ======
__global__ __launch_bounds__(256) void gat_agg_h1_kernel(
    const int* __restrict__ csr_src, const int* __restrict__ rowptr,
    const int* __restrict__ deg, const unsigned short* __restrict__ h,
    const float* __restrict__ als, const float* __restrict__ ald,
    const float* __restrict__ bias, float* __restrict__ out, int n) {
    const int lane = threadIdx.x & 63;
    const int node = (blockIdx.x << 2) + (threadIdx.x >> 6);
    if (node >= n) return;
    const int start = rowptr[node];
    const int len = deg[node];
    const float ad = ald[node];
    float m = -1e30f, z = 0.f, acc = 0.f;
    int k = 0;
    for (; k + 4 <= len; k += 4) {
        int s0 = csr_src[start + k + 0];
        int s1 = csr_src[start + k + 1];
        int s2 = csr_src[start + k + 2];
        int s3 = csr_src[start + k + 3];
        float a0 = als[s0], a1 = als[s1], a2 = als[s2], a3 = als[s3];
        float h0 = bf2f(h[((size_t)s0 << 6) + lane]);
        float h1 = bf2f(h[((size_t)s1 << 6) + lane]);
        float h2 = bf2f(h[((size_t)s2 << 6) + lane]);
        float h3 = bf2f(h[((size_t)s3 << 6) + lane]);
        float x0 = a0 + ad; x0 = (x0 > 0.f) ? x0 : 0.2f * x0;
        float x1 = a1 + ad; x1 = (x1 > 0.f) ? x1 : 0.2f * x1;
        float x2 = a2 + ad; x2 = (x2 > 0.f) ? x2 : 0.2f * x2;
        float x3 = a3 + ad; x3 = (x3 > 0.f) ? x3 : 0.2f * x3;
        float nm = fmaxf(fmaxf(fmaxf(x0, x1), fmaxf(x2, x3)), m);
        float c  = __expf(m - nm);
        float p0 = __expf(x0 - nm), p1 = __expf(x1 - nm);
        float p2 = __expf(x2 - nm), p3 = __expf(x3 - nm);
        m = nm;
        z = z * c + p0 + p1 + p2 + p3;
        acc = acc * c + p0 * h0 + p1 * h1 + p2 * h2 + p3 * h3;
    }
    for (; k < len; k++) {
        int s0 = csr_src[start + k];
        float x0 = als[s0] + ad; x0 = (x0 > 0.f) ? x0 : 0.2f * x0;
        float h0 = bf2f(h[((size_t)s0 << 6) + lane]);
        float nm = fmaxf(m, x0);
        float c  = __expf(m - nm);
        float p0 = __expf(x0 - nm);
        m = nm;
        z = z * c + p0;
        acc = acc * c + p0 * h0;
    }
    out[((size_t)node << 6) + lane] = acc / (z + 1e-16f) + bias[lane];
}

// ---------- mean pooling over (sorted) batch via binary search ----------
__global__ __launch_bounds__(64) void pool_kernel(const float* __restrict__ h3,
                                                  const int* __restrict__ batch,
                                                  float* __restrict__ xg) {
    const int b = blockIdx.x;
    const int j = threadIdx.x;
    int lo = 0, hi = N_NODES;
    while (lo < hi) { int mid = (lo + hi) >> 1; if (batch[mid] < b) lo = mid + 1; else hi = mid; }
    const int start = lo;
    hi = N_NODES;
    while (lo < hi) { int mid = (lo + hi) >> 1; if (batch[mid] < b + 1) lo = mid + 1; else hi = mid; }
    const int end = lo;
    float s = 0.f;
    for (int n = start; n < end; n++) s += h3[(size_t)n * CH + j];
    xg[b * CH + j] = s / fmaxf((float)(end - start), 1.f);
}

// ---------- MLP layer 2 + LayerNorm, one block per graph ----------
__global__ __launch_bounds__(256) void mlp2_ln_kernel(
    const float* __restrict__ y1, const float* __restrict__ Wm2,
    const float* __restrict__ bm2, const float* __restrict__ g2,
    const float* __restrict__ be2, float* __restrict__ out) {
    const int b = blockIdx.x;
    const int j = threadIdx.x;
    __shared__ float yr[NHID];
    yr[j] = y1[(size_t)b * NHID + j];
    __syncthreads();
    float acc = bm2[j];
#pragma unroll 8
    for (int k = 0; k < NHID; k++) acc += yr[k] * Wm2[(size_t)k * NOUT + j];
    float s = acc, s2 = acc * acc;
    for (int o = 32; o > 0; o >>= 1) {
        s += __shfl_down(s, o);
        s2 += __shfl_down(s2, o);
    }
    __shared__ float red[8];
    __shared__ float mv[2];
    int wave = j >> 6, lane = j & 63;
    if (lane == 0) { red[wave] = s; red[4 + wave] = s2; }
    __syncthreads();
    if (j == 0) {
        float ts = red[0] + red[1] + red[2] + red[3];
        float ts2 = red[4] + red[5] + red[6] + red[7];
        float mu = ts / (float)NOUT;
        float var = ts2 / (float)NOUT - mu * mu;
        mv[0] = mu;
        mv[1] = rsqrtf(var + 1e-5f);
    }
    __syncthreads();
    out[(size_t)b * NOUT + j] = (acc - mv[0]) * mv[1] * g2[j] + be2[j];
}

extern "C" void kernel_launch(void* const* d_in, const int* in_sizes, int n_in,
                              void* d_out, int out_size, void* d_ws, size_t ws_size,
                              hipStream_t stream) {
    const float* x      = (const float*)d_in[0];
    const int*   ei     = (const int*)d_in[1];
    const int*   batch  = (const int*)d_in[2];
    const float* W1     = (const float*)d_in[3];
    const float* as1    = (const float*)d_in[4];
    const float* ad1    = (const float*)d_in[5];
    const float* b1     = (const float*)d_in[6];
    const float* W2     = (const float*)d_in[7];
    const float* as2    = (const float*)d_in[8];
    const float* ad2    = (const float*)d_in[9];
    const float* b2     = (const float*)d_in[10];
    const float* W3     = (const float*)d_in[11];
    const float* as3    = (const float*)d_in[12];
    const float* ad3    = (const float*)d_in[13];
    const float* b3     = (const float*)d_in[14];
    const float* Wm1    = (const float*)d_in[15];
    const float* bm1    = (const float*)d_in[16];
    const float* Wm2    = (const float*)d_in[17];
    const float* bm2    = (const float*)d_in[18];
    const float* g2     = (const float*)d_in[19];
    const float* be2    = (const float*)d_in[20];
    float* out = (float*)d_out;

    // workspace layout
    float* bufO = (float*)d_ws;                              // N*HC fp32
    float* als  = bufO + (size_t)N_NODES * HC;               // N*HEADS
    float* ald  = als + (size_t)N_NODES * HEADS;             // N*HEADS
    float* xg   = ald + (size_t)N_NODES * HEADS;             // NB*CH
    float* y1   = xg + (size_t)NB * CH;                      // NB*NHID
    unsigned short* bufH = (unsigned short*)(y1 + (size_t)NB * NHID);  // N*HC bf16
    int* deg     = (int*)(bufH + (size_t)N_NODES * HC);      // N
    int* rowptr  = deg + N_NODES;                            // N
    int* cursor  = rowptr + N_NODES;                         // N
    int* bsum    = cursor + N_NODES;                         // <=64
    int* csr_src = bsum + 64;                                // E2
    unsigned short* wt1h = (unsigned short*)(csr_src + E2_EDGES);  // 256*32
    unsigned short* wt1l = wt1h + 256 * 32;
    unsigned short* wt2h = wt1l + 256 * 32;                        // 256*256
    unsigned short* wt2l = wt2h + 256 * 256;
    unsigned short* wt3h = wt2l + 256 * 256;                       // 64*256
    unsigned short* wt3l = wt3h + 64 * 256;

    const int BLK = 256;
    const int NSCAN = cdiv(N_NODES, 1024);

    // ===================== weight prep (fragment-major split bf16) ==========
    wconv_frag_kernel<<<cdiv(F_IN * HC, BLK), BLK, 0, stream>>>(W1, wt1h, wt1l, F_IN, HC);
    wconv_frag_kernel<<<cdiv(HC * HC, BLK), BLK, 0, stream>>>(W2, wt2h, wt2l, HC, HC);
    wconv_frag_kernel<<<cdiv(HC * CH, BLK), BLK, 0, stream>>>(W3, wt3h, wt3l, HC, CH);

    // ===================== CSR build (dst-sorted adjacency) ==================
    hipMemsetAsync(deg, 0, (size_t)N_NODES * sizeof(int), stream);
    hist_kernel<<<cdiv(E2_EDGES, BLK), BLK, 0, stream>>>(ei, deg);
    scan_block_kernel<<<NSCAN, 256, 0, stream>>>(deg, rowptr, bsum);
    scan_bsum_kernel<<<1, 64, 0, stream>>>(bsum, NSCAN);
    finalize_rowptr_kernel<<<cdiv(N_NODES, BLK), BLK, 0, stream>>>(rowptr, bsum, cursor);
    scatter_kernel<<<cdiv(E2_EDGES, BLK), BLK, 0, stream>>>(ei, cursor, csr_src);

    // ===================== Layer 1 (F_IN -> H*C) =====================
    mfma_lin_reg_kernel<F_IN, HC, 128, true><<<cdiv(N_NODES, 64), 256, 0, stream>>>(
        x, wt1h, wt1l, nullptr, bufH, N_NODES);
    attn_logits_kernel<HEADS, CH><<<cdiv((long long)N_NODES * HEADS, BLK), BLK, 0, stream>>>(
        bufH, as1, ad1, als, ald, N_NODES);
    gat_agg_wide_kernel<true><<<cdiv(N_NODES, 4), 256, 0, stream>>>(
        csr_src, rowptr, deg, bufH, als, ald, b1, bufO, N_NODES);

    // ===================== Layer 2 (H*C -> H*C) =====================
    mfma_lin_reg_kernel<HC, HC, 128, true><<<cdiv(N_NODES, 64), 256, 0, stream>>>(
        bufO, wt2h, wt2l, nullptr, bufH, N_NODES);
    attn_logits_kernel<HEADS, CH><<<cdiv((long long)N_NODES * HEADS, BLK), BLK, 0, stream>>>(
        bufH, as2, ad2, als, ald, N_NODES);
    gat_agg_wide_kernel<true><<<cdiv(N_NODES, 4), 256, 0, stream>>>(
        csr_src, rowptr, deg, bufH, als, ald, b2, bufO, N_NODES);

    // ===================== Layer 3 (H*C -> C, heads=1) =====================
    mfma_lin_reg_kernel<HC, CH, 64, true><<<cdiv(N_NODES, 128), 256, 0, stream>>>(
        bufO, wt3h, wt3l, nullptr, bufH, N_NODES);
    attn_logits_kernel<1, CH><<<cdiv(N_NODES, BLK), BLK, 0, stream>>>(
        bufH, as3, ad3, als, ald, N_NODES);
    gat_agg_h1_kernel<<<cdiv(N_NODES, 4), 256, 0, stream>>>(
        csr_src, rowptr, deg, bufH, als, ald, b3, bufO, N_NODES);

    // ===================== Mean pooling (batch is sorted) =====================
    pool_kernel<<<NB, 64, 0, stream>>>(bufO, batch, xg);

    // ===================== MLP head + LayerNorm =====================
    lin_kernel<CH, NHID, 16, 256, true><<<cdiv(NB, 16), 256, 0, stream>>>(
        xg, Wm1, bm1, y1, NB);
    mlp2_ln_kernel<<<NB, 256, 0, stream>>>(y1, Wm2, bm2, g2, be2, out);
}

// Round 9
// 472.423 us; speedup vs baseline: 1.1030x; 1.0239x over previous
//
#include <hip/hip_runtime.h>
#include <hip/hip_bf16.h>

#define N_NODES 50000
#define N_EDGES 500000
#define E2_EDGES 550000   // with self loops appended
#define F_IN 32
#define HEADS 4
#define CH 64
#define HC 256            // HEADS*CH
#define NB 1000
#define NHID 256
#define NOUT 256

static inline int cdiv(long long a, long long b) { return (int)((a + b - 1) / b); }

typedef __bf16 bf16x8 __attribute__((ext_vector_type(8)));
typedef unsigned short us8 __attribute__((ext_vector_type(8)));
typedef unsigned short us4 __attribute__((ext_vector_type(4)));
typedef float f32x4 __attribute__((ext_vector_type(4)));
union BU { us8 u; bf16x8 b; };

// round-to-nearest-even fp32 -> bf16 (bit pattern)
__device__ inline unsigned short f2bf(float f) {
    unsigned u = __float_as_uint(f);
    return (unsigned short)((u + 0x7fffu + ((u >> 16) & 1u)) >> 16);
}
__device__ inline float bf2f(unsigned short h) {
    return __uint_as_float(((unsigned)h) << 16);
}

// ---------- split fp32 array -> (hi,lo) bf16 planes ----------
__global__ void split_kernel(const float* __restrict__ in,
                             unsigned short* __restrict__ oh,
                             unsigned short* __restrict__ ol, int n) {
    int i = blockIdx.x * blockDim.x + threadIdx.x;
    if (i >= n) return;
    float v = in[i];
    unsigned short hi = f2bf(v);
    oh[i] = hi;
    ol[i] = f2bf(v - bf2f(hi));
}

// ---------- W prep: split fp32 -> (hi,lo) bf16 in MFMA-fragment-major order --
// Wf[((tcol*NCH + ch)*64 + lane)*8 + j]: lane=quad*16+l16 holds
// W[ch*32+quad*8+j][tcol*16+l16]. Wave B-load = base + lane*16B (coalesced 1KB).
__global__ void wconv_frag_kernel(const float* __restrict__ W,
                                  unsigned short* __restrict__ Wf_hi,
                                  unsigned short* __restrict__ Wf_lo, int K, int M) {
    int idx = blockIdx.x * blockDim.x + threadIdx.x;
    if (idx >= K * M) return;
    int k = idx / M, m = idx % M;
    float v = W[idx];
    unsigned short hi = f2bf(v);
    unsigned short lo = f2bf(v - bf2f(hi));
    int tcol = m >> 4, l16 = m & 15;
    int ch = k >> 5, quad = (k >> 3) & 3, j = k & 7;
    int NCH = K >> 5;
    size_t dst = ((((size_t)tcol * NCH + ch) * 64) + quad * 16 + l16) * 8 + j;
    Wf_hi[dst] = hi;
    Wf_lo[dst] = lo;
}

// ---------- barrier-free software-pipelined split-bf16 MFMA GEMM ----------
// C[N,M] = A[N,K] @ W[K,M]. A given as hi/lo bf16 planes; Wf_* fragment-major.
// Ping-pong register buffers: chunk ch+1 loads issued before chunk ch MFMAs.
template<int K, int M, int WT, bool OBF>
__global__ __launch_bounds__(256) void mfma_lin_pipe_kernel(
    const unsigned short* __restrict__ Ah, const unsigned short* __restrict__ Al,
    const unsigned short* __restrict__ Wf_hi, const unsigned short* __restrict__ Wf_lo,
    const float* __restrict__ bias, void* __restrict__ Cout, int n_rows) {
    constexpr int NT = WT / 16;     // col tiles per wave
    constexpr int NCH = K / 32;     // K chunks
    constexpr int CW = M / WT;      // col waves per block
    constexpr int RW = 4 / CW;      // row waves per block
    const int wave = threadIdx.x >> 6, lane = threadIdx.x & 63;
    const int quad = lane >> 4, l16 = lane & 15;
    const int col0 = (wave % CW) * WT;
    const int row0 = blockIdx.x * (RW * 32) + (wave / CW) * 32;

    f32x4 acc[2][NT];
#pragma unroll
    for (int rs = 0; rs < 2; rs++)
#pragma unroll
        for (int t = 0; t < NT; t++) acc[rs][t] = (f32x4){0.f, 0.f, 0.f, 0.f};

    const int r0 = min(row0 + l16, n_rows - 1);
    const int r1 = min(row0 + 16 + l16, n_rows - 1);
    const unsigned short* a0h = Ah + (size_t)r0 * K + quad * 8;
    const unsigned short* a0l = Al + (size_t)r0 * K + quad * 8;
    const unsigned short* a1h = Ah + (size_t)r1 * K + quad * 8;
    const unsigned short* a1l = Al + (size_t)r1 * K + quad * 8;
    const unsigned short* bh = Wf_hi + ((size_t)(col0 >> 4) * NCH * 64 + lane) * 8;
    const unsigned short* bl = Wf_lo + ((size_t)(col0 >> 4) * NCH * 64 + lane) * 8;

    BU cah[2][2], cal[2][2];     // [buf][rowset]
    BU cbh[2][NT], cbl[2][NT];   // [buf][tile]

    // preload chunk 0 into buffer 0
    cah[0][0].u = *(const us8*)a0h;
    cal[0][0].u = *(const us8*)a0l;
    cah[0][1].u = *(const us8*)a1h;
    cal[0][1].u = *(const us8*)a1l;
#pragma unroll
    for (int t = 0; t < NT; t++) {
        cbh[0][t].u = *(const us8*)(bh + (size_t)(t * NCH) * 512);
        cbl[0][t].u = *(const us8*)(bl + (size_t)(t * NCH) * 512);
    }

#pragma unroll
    for (int ch = 0; ch < NCH; ch++) {
        const int cur = ch & 1, nxt = cur ^ 1;
        if (ch + 1 < NCH) {
            // prefetch chunk ch+1 (loads in flight across current MFMAs)
            cah[nxt][0].u = *(const us8*)(a0h + (ch + 1) * 32);
            cal[nxt][0].u = *(const us8*)(a0l + (ch + 1) * 32);
            cah[nxt][1].u = *(const us8*)(a1h + (ch + 1) * 32);
            cal[nxt][1].u = *(const us8*)(a1l + (ch + 1) * 32);
#pragma unroll
            for (int t = 0; t < NT; t++) {
                cbh[nxt][t].u = *(const us8*)(bh + (size_t)(t * NCH + ch + 1) * 512);
                cbl[nxt][t].u = *(const us8*)(bl + (size_t)(t * NCH + ch + 1) * 512);
            }
        }
#pragma unroll
        for (int t = 0; t < NT; t++) {
#pragma unroll
            for (int rs = 0; rs < 2; rs++) {
                acc[rs][t] = __builtin_amdgcn_mfma_f32_16x16x32_bf16(cah[cur][rs].b, cbh[cur][t].b, acc[rs][t], 0, 0, 0);
                acc[rs][t] = __builtin_amdgcn_mfma_f32_16x16x32_bf16(cah[cur][rs].b, cbl[cur][t].b, acc[rs][t], 0, 0, 0);
                acc[rs][t] = __builtin_amdgcn_mfma_f32_16x16x32_bf16(cal[cur][rs].b, cbh[cur][t].b, acc[rs][t], 0, 0, 0);
            }
        }
    }
    // epilogue: row = row0 + rs*16 + quad*4 + i, col = col0 + t*16 + l16
#pragma unroll
    for (int rs = 0; rs < 2; rs++) {
        const int orow0 = row0 + rs * 16 + quad * 4;
#pragma unroll
        for (int t = 0; t < NT; t++) {
            float bv = bias ? bias[col0 + t * 16 + l16] : 0.f;
#pragma unroll
            for (int i = 0; i < 4; i++) {
                int r = orow0 + i;
                if (r < n_rows) {
                    float v = acc[rs][t][i] + bv;
                    if (OBF) ((unsigned short*)Cout)[(size_t)r * M + col0 + t * 16 + l16] = f2bf(v);
                    else     ((float*)Cout)[(size_t)r * M + col0 + t * 16 + l16] = v;
                }
            }
        }
    }
}

// ---------- generic small GEMM (MLP layer 1) ----------
template<int K, int M, int TM, int BLOCK, bool RELU>
__global__ __launch_bounds__(BLOCK) void lin_kernel(
    const float* __restrict__ A, const float* __restrict__ W,
    const float* __restrict__ bias, float* __restrict__ C, int n_rows) {
    __shared__ float As[TM][K];
    const int n0 = blockIdx.x * TM;
    const int tid = threadIdx.x;
    for (int idx = tid; idx < TM * K; idx += BLOCK) {
        int r = idx / K, c = idx % K;
        int n = n0 + r;
        As[r][c] = (n < n_rows) ? A[(size_t)n * K + c] : 0.f;
    }
    __syncthreads();
    constexpr int G = BLOCK / M;
    constexpr int RPT = TM / G;
    const int j = tid % M;
    const int g = tid / M;
    float acc[RPT];
#pragma unroll
    for (int i = 0; i < RPT; i++) acc[i] = 0.f;
    for (int k = 0; k < K; k++) {
        float wk = W[(size_t)k * M + j];
#pragma unroll
        for (int i = 0; i < RPT; i++) acc[i] += As[g * RPT + i][k] * wk;
    }
    float bv = bias ? bias[j] : 0.f;
#pragma unroll
    for (int i = 0; i < RPT; i++) {
        int n = n0 + g * RPT + i;
        if (n < n_rows) {
            float v = acc[i] + bv;
            if (RELU) v = fmaxf(v, 0.f);
            C[(size_t)n * M + j] = v;
        }
    }
}

// ---------- per-(node,head) attention logits from bf16 h ----------
template<int H_, int C_>
__global__ void attn_logits_kernel(const unsigned short* __restrict__ h,
                                   const float* __restrict__ a_src,
                                   const float* __restrict__ a_dst,
                                   float* __restrict__ als, float* __restrict__ ald,
                                   int n) {
    int t = blockIdx.x * blockDim.x + threadIdx.x;
    if (t >= n * H_) return;
    int node = t / H_, hh = t % H_;
    const us8* hp = (const us8*)(h + (size_t)node * (H_ * C_) + hh * C_);
    const float4* as = (const float4*)(a_src + hh * C_);
    const float4* ad = (const float4*)(a_dst + hh * C_);
    float ss = 0.f, sd = 0.f;
#pragma unroll
    for (int c = 0; c < C_ / 8; c++) {
        us8 hv = hp[c];
        float4 a0 = as[2 * c], a1 = as[2 * c + 1];
        float4 b0 = ad[2 * c], b1 = ad[2 * c + 1];
        float f0 = bf2f(hv[0]), f1 = bf2f(hv[1]), f2 = bf2f(hv[2]), f3 = bf2f(hv[3]);
        float f4 = bf2f(hv[4]), f5 = bf2f(hv[5]), f6 = bf2f(hv[6]), f7 = bf2f(hv[7]);
        ss += f0 * a0.x + f1 * a0.y + f2 * a0.z + f3 * a0.w
            + f4 * a1.x + f5 * a1.y + f6 * a1.z + f7 * a1.w;
        sd += f0 * b0.x + f1 * b0.y + f2 * b0.z + f3 * b0.w
            + f4 * b1.x + f5 * b1.y + f6 * b1.z + f7 * b1.w;
    }
    als[t] = ss;
    ald[t] = sd;
}

// ======================= CSR build =======================
__global__ void hist_kernel(const int* __restrict__ ei, int* __restrict__ deg) {
    int e = blockIdx.x * blockDim.x + threadIdx.x;
    if (e >= E2_EDGES) return;
    int d = (e < N_EDGES) ? ei[N_EDGES + e] : (e - N_EDGES);
    atomicAdd(deg + d, 1);
}

__global__ __launch_bounds__(256) void scan_block_kernel(const int* __restrict__ deg,
                                                         int* __restrict__ rowptr,
                                                         int* __restrict__ bsum) {
    __shared__ int sdata[256];
    const int b = blockIdx.x, t = threadIdx.x;
    const int base = b * 1024 + t * 4;
    int v[4]; int s = 0;
#pragma unroll
    for (int i = 0; i < 4; i++) {
        int idx = base + i;
        v[i] = (idx < N_NODES) ? deg[idx] : 0;
        s += v[i];
    }
    sdata[t] = s;
    __syncthreads();
    for (int o = 1; o < 256; o <<= 1) {
        int x = (t >= o) ? sdata[t - o] : 0;
        __syncthreads();
        sdata[t] += x;
        __syncthreads();
    }
    if (t == 255) bsum[b] = sdata[255];
    int run = sdata[t] - s;
#pragma unroll
    for (int i = 0; i < 4; i++) {
        int idx = base + i;
        if (idx < N_NODES) rowptr[idx] = run;
        run += v[i];
    }
}

__global__ void scan_bsum_kernel(int* __restrict__ bsum, int nb) {
    if (threadIdx.x == 0 && blockIdx.x == 0) {
        int run = 0;
        for (int i = 0; i < nb; i++) { int v = bsum[i]; bsum[i] = run; run += v; }
    }
}

__global__ void finalize_rowptr_kernel(int* __restrict__ rowptr, const int* __restrict__ bsum,
                                       int* __restrict__ cursor) {
    int i = blockIdx.x * blockDim.x + threadIdx.x;
    if (i >= N_NODES) return;
    int v = rowptr[i] + bsum[i >> 10];
    rowptr[i] = v;
    cursor[i] = v;
}

__global__ void scatter_kernel(const int* __restrict__ ei, int* __restrict__ cursor,
                               int* __restrict__ csr_src) {
    int e = blockIdx.x * blockDim.x + threadIdx.x;
    if (e >= E2_EDGES) return;
    int s, d;
    if (e < N_EDGES) { s = ei[e]; d = ei[N_EDGES + e]; }
    else             { s = d = e - N_EDGES; }
    int pos = atomicAdd(cursor + d, 1);
    csr_src[pos] = s;
}

// ===== wide GAT agg: 1 wave/node, lane owns 4 ch; writes hi/lo bf16 planes ===
__global__ __launch_bounds__(256) void gat_agg_wide_kernel(
    const int* __restrict__ csr_src, const int* __restrict__ rowptr,
    const int* __restrict__ deg, const unsigned short* __restrict__ h,
    const float* __restrict__ als, const float* __restrict__ ald,
    const float* __restrict__ bias, unsigned short* __restrict__ outh,
    unsigned short* __restrict__ outl, int n) {
    const int lane = threadIdx.x & 63;
    const int node = (blockIdx.x << 2) + (threadIdx.x >> 6);
    if (node >= n) return;
    const int hh = lane >> 4;
    const int start = rowptr[node];
    const int len = deg[node];
    const float ad = ald[(node << 2) + hh];
    float m = -1e30f, z = 0.f;
    float4 acc = make_float4(0.f, 0.f, 0.f, 0.f);
    int k = 0;
    for (; k + 4 <= len; k += 4) {
        int s0 = csr_src[start + k + 0];
        int s1 = csr_src[start + k + 1];
        int s2 = csr_src[start + k + 2];
        int s3 = csr_src[start + k + 3];
        float a0 = als[(s0 << 2) + hh], a1 = als[(s1 << 2) + hh];
        float a2 = als[(s2 << 2) + hh], a3 = als[(s3 << 2) + hh];
        us4 h0 = *(const us4*)(h + ((size_t)s0 << 8) + (lane << 2));
        us4 h1 = *(const us4*)(h + ((size_t)s1 << 8) + (lane << 2));
        us4 h2 = *(const us4*)(h + ((size_t)s2 << 8) + (lane << 2));
        us4 h3 = *(const us4*)(h + ((size_t)s3 << 8) + (lane << 2));
        float x0 = a0 + ad; x0 = (x0 > 0.f) ? x0 : 0.2f * x0;
        float x1 = a1 + ad; x1 = (x1 > 0.f) ? x1 : 0.2f * x1;
        float x2 = a2 + ad; x2 = (x2 > 0.f) ? x2 : 0.2f * x2;
        float x3 = a3 + ad; x3 = (x3 > 0.f) ? x3 : 0.2f * x3;
        float nm = fmaxf(fmaxf(fmaxf(x0, x1), fmaxf(x2, x3)), m);
        float c  = __expf(m - nm);
        float p0 = __expf(x0 - nm), p1 = __expf(x1 - nm);
        float p2 = __expf(x2 - nm), p3 = __expf(x3 - nm);
        m = nm;
        z = z * c + p0 + p1 + p2 + p3;
        acc.x = acc.x * c + p0 * bf2f(h0[0]) + p1 * bf2f(h1[0]) + p2 * bf2f(h2[0]) + p3 * bf2f(h3[0]);
        acc.y = acc.y * c + p0 * bf2f(h0[1]) + p1 * bf2f(h1[1]) + p2 * bf2f(h2[1]) + p3 * bf2f(h3[1]);
        acc.z = acc.z * c + p0 * bf2f(h0[2]) + p1 * bf2f(h1[2]) + p2 * bf2f(h2[2]) + p3 * bf2f(h3[2]);
        acc.w = acc.w * c + p0 * bf2f(h0[3]) + p1 * bf2f(h1[3]) + p2 * bf2f(h2[3]) + p3 * bf2f(h3[3]);
    }
    for (; k < len; k++) {
        int s0 = csr_src[start + k];
        float x0 = als[(s0 << 2) + hh] + ad; x0 = (x0 > 0.f) ? x0 : 0.2f * x0;
        us4 h0 = *(const us4*)(h + ((size_t)s0 << 8) + (lane << 2));
        float nm = fmaxf(m, x0);
        float c  = __expf(m - nm);
        float p0 = __expf(x0 - nm);
        m = nm;
        z = z * c + p0;
        acc.x = acc.x * c + p0 * bf2f(h0[0]);
        acc.y = acc.y * c + p0 * bf2f(h0[1]);
        acc.z = acc.z * c + p0 * bf2f(h0[2]);
        acc.w = acc.w * c + p0 * bf2f(h0[3]);
    }
    float inv = 1.f / (z + 1e-16f);
    float4 bv = *(const float4*)(bias + (lane << 2));
    float v[4];
    v[0] = fmaxf(acc.x * inv + bv.x, 0.f);   // relu=true for layers 1,2
    v[1] = fmaxf(acc.y * inv + bv.y, 0.f);
    v[2] = fmaxf(acc.z * inv + bv.z, 0.f);
    v[3] = fmaxf(acc.w * inv + bv.w, 0.f);
    us4 vh, vl;
#pragma unroll
    for (int i = 0; i < 4; i++) {
        unsigned short hi = f2bf(v[i]);
        vh[i] = hi;
        vl[i] = f2bf(v[i] - bf2f(hi));
    }
    *(us4*)(outh + ((size_t)node << 8) + (lane << 2)) = vh;
    *(us4*)(outl + ((size_t)node << 8) + (lane << 2)) = vl;
}

// ======================= layer-3 agg: H=1, C=64 (bf16 h, fp32 out) ======
__global__ __launch_bounds__(256) void gat_agg_h1_kernel(
    const int* __restrict__ csr_src, const int* __restrict__ rowptr,
    const int* __restrict__ deg, const unsigned short* __restrict__ h,
    const float* __restrict__ als, const float* __restrict__ ald,
    const float* __restrict__ bias, float* __restrict__ out, int n) {
    const int lane = threadIdx.x & 63;
    const int node = (blockIdx.x << 2) + (threadIdx.x >> 6);
    if (node >= n) return;
    const int start = rowptr[node];
    const int len = deg[node];
    const float ad = ald[node];
    float m = -1e30f, z = 0.f, acc = 0.f;
    int k = 0;
    for (; k + 4 <= len; k += 4) {
        int s0 = csr_src[start + k + 0];
        int s1 = csr_src[start + k + 1];
        int s2 = csr_src[start + k + 2];
        int s3 = csr_src[start + k + 3];
        float a0 = als[s0], a1 = als[s1], a2 = als[s2], a3 = als[s3];
        float h0 = bf2f(h[((size_t)s0 << 6) + lane]);
        float h1 = bf2f(h[((size_t)s1 << 6) + lane]);
        float h2 = bf2f(h[((size_t)s2 << 6) + lane]);
        float h3 = bf2f(h[((size_t)s3 << 6) + lane]);
        float x0 = a0 + ad; x0 = (x0 > 0.f) ? x0 : 0.2f * x0;
        float x1 = a1 + ad; x1 = (x1 > 0.f) ? x1 : 0.2f * x1;
        float x2 = a2 + ad; x2 = (x2 > 0.f) ? x2 : 0.2f * x2;
        float x3 = a3 + ad; x3 = (x3 > 0.f) ? x3 : 0.2f * x3;
        float nm = fmaxf(fmaxf(fmaxf(x0, x1), fmaxf(x2, x3)), m);
        float c  = __expf(m - nm);
        float p0 = __expf(x0 - nm), p1 = __expf(x1 - nm);
        float p2 = __expf(x2 - nm), p3 = __expf(x3 - nm);
        m = nm;
        z = z * c + p0 + p1 + p2 + p3;
        acc = acc * c + p0 * h0 + p1 * h1 + p2 * h2 + p3 * h3;
    }
    for (; k < len; k++) {
        int s0 = csr_src[start + k];
        float x0 = als[s0] + ad; x0 = (x0 > 0.f) ? x0 : 0.2f * x0;
        float h0 = bf2f(h[((size_t)s0 << 6) + lane]);
        float nm = fmaxf(m, x0);
        float c  = __expf(m - nm);
        float p0 = __expf(x0 - nm);
        m = nm;
        z = z * c + p0;
        acc = acc * c + p0 * h0;
    }
    out[((size_t)node << 6) + lane] = acc / (z + 1e-16f) + bias[lane];
}

// ---------- mean pooling over (sorted) batch via binary search ----------
__global__ __launch_bounds__(64) void pool_kernel(const float* __restrict__ h3,
                                                  const int* __restrict__ batch,
                                                  float* __restrict__ xg) {
    const int b = blockIdx.x;
    const int j = threadIdx.x;
    int lo = 0, hi = N_NODES;
    while (lo < hi) { int mid = (lo + hi) >> 1; if (batch[mid] < b) lo = mid + 1; else hi = mid; }
    const int start = lo;
    hi = N_NODES;
    while (lo < hi) { int mid = (lo + hi) >> 1; if (batch[mid] < b + 1) lo = mid + 1; else hi = mid; }
    const int end = lo;
    float s = 0.f;
    for (int n = start; n < end; n++) s += h3[(size_t)n * CH + j];
    xg[b * CH + j] = s / fmaxf((float)(end - start), 1.f);
}

// ---------- MLP layer 2 + LayerNorm, one block per graph ----------
__global__ __launch_bounds__(256) void mlp2_ln_kernel(
    const float* __restrict__ y1, const float* __restrict__ Wm2,
    const float* __restrict__ bm2, const float* __restrict__ g2,
    const float* __restrict__ be2, float* __restrict__ out) {
    const int b = blockIdx.x;
    const int j = threadIdx.x;
    __shared__ float yr[NHID];
    yr[j] = y1[(size_t)b * NHID + j];
    __syncthreads();
    float acc = bm2[j];
#pragma unroll 8
    for (int k = 0; k < NHID; k++) acc += yr[k] * Wm2[(size_t)k * NOUT + j];
    float s = acc, s2 = acc * acc;
    for (int o = 32; o > 0; o >>= 1) {
        s += __shfl_down(s, o);
        s2 += __shfl_down(s2, o);
    }
    __shared__ float red[8];
    __shared__ float mv[2];
    int wave = j >> 6, lane = j & 63;
    if (lane == 0) { red[wave] = s; red[4 + wave] = s2; }
    __syncthreads();
    if (j == 0) {
        float ts = red[0] + red[1] + red[2] + red[3];
        float ts2 = red[4] + red[5] + red[6] + red[7];
        float mu = ts / (float)NOUT;
        float var = ts2 / (float)NOUT - mu * mu;
        mv[0] = mu;
        mv[1] = rsqrtf(var + 1e-5f);
    }
    __syncthreads();
    out[(size_t)b * NOUT + j] = (acc - mv[0]) * mv[1] * g2[j] + be2[j];
}

extern "C" void kernel_launch(void* const* d_in, const int* in_sizes, int n_in,
                              void* d_out, int out_size, void* d_ws, size_t ws_size,
                              hipStream_t stream) {
    const float* x      = (const float*)d_in[0];
    const int*   ei     = (const int*)d_in[1];
    const int*   batch  = (const int*)d_in[2];
    const float* W1     = (const float*)d_in[3];
    const float* as1    = (const float*)d_in[4];
    const float* ad1    = (const float*)d_in[5];
    const float* b1     = (const float*)d_in[6];
    const float* W2     = (const float*)d_in[7];
    const float* as2    = (const float*)d_in[8];
    const float* ad2    = (const float*)d_in[9];
    const float* b2     = (const float*)d_in[10];
    const float* W3     = (const float*)d_in[11];
    const float* as3    = (const float*)d_in[12];
    const float* ad3    = (const float*)d_in[13];
    const float* b3     = (const float*)d_in[14];
    const float* Wm1    = (const float*)d_in[15];
    const float* bm1    = (const float*)d_in[16];
    const float* Wm2    = (const float*)d_in[17];
    const float* bm2    = (const float*)d_in[18];
    const float* g2     = (const float*)d_in[19];
    const float* be2    = (const float*)d_in[20];
    float* out = (float*)d_out;

    // workspace layout
    unsigned short* bufH = (unsigned short*)d_ws;                  // N*HC bf16 (GEMM out)
    unsigned short* aggh = bufH + (size_t)N_NODES * HC;            // N*HC
    unsigned short* aggl = aggh + (size_t)N_NODES * HC;            // N*HC
    unsigned short* xh   = aggl + (size_t)N_NODES * HC;            // N*F_IN
    unsigned short* xl   = xh + (size_t)N_NODES * F_IN;            // N*F_IN
    float* bufO3 = (float*)(xl + (size_t)N_NODES * F_IN);          // N*CH fp32
    float* als   = bufO3 + (size_t)N_NODES * CH;                   // N*HEADS
    float* ald   = als + (size_t)N_NODES * HEADS;                  // N*HEADS
    float* xg    = ald + (size_t)N_NODES * HEADS;                  // NB*CH
    float* y1    = xg + (size_t)NB * CH;                           // NB*NHID
    int* deg     = (int*)(y1 + (size_t)NB * NHID);                 // N
    int* rowptr  = deg + N_NODES;                                  // N
    int* cursor  = rowptr + N_NODES;                               // N
    int* bsum    = cursor + N_NODES;                               // <=64
    int* csr_src = bsum + 64;                                      // E2
    unsigned short* wt1h = (unsigned short*)(csr_src + E2_EDGES);  // 256*32
    unsigned short* wt1l = wt1h + 256 * 32;
    unsigned short* wt2h = wt1l + 256 * 32;                        // 256*256
    unsigned short* wt2l = wt2h + 256 * 256;
    unsigned short* wt3h = wt2l + 256 * 256;                       // 64*256
    unsigned short* wt3l = wt3h + 64 * 256;

    const int BLK = 256;
    const int NSCAN = cdiv(N_NODES, 1024);

    // ===================== weight + input prep ==============================
    wconv_frag_kernel<<<cdiv(F_IN * HC, BLK), BLK, 0, stream>>>(W1, wt1h, wt1l, F_IN, HC);
    wconv_frag_kernel<<<cdiv(HC * HC, BLK), BLK, 0, stream>>>(W2, wt2h, wt2l, HC, HC);
    wconv_frag_kernel<<<cdiv(HC * CH, BLK), BLK, 0, stream>>>(W3, wt3h, wt3l, HC, CH);
    split_kernel<<<cdiv(N_NODES * F_IN, BLK), BLK, 0, stream>>>(x, xh, xl, N_NODES * F_IN);

    // ===================== CSR build (dst-sorted adjacency) ==================
    hipMemsetAsync(deg, 0, (size_t)N_NODES * sizeof(int), stream);
    hist_kernel<<<cdiv(E2_EDGES, BLK), BLK, 0, stream>>>(ei, deg);
    scan_block_kernel<<<NSCAN, 256, 0, stream>>>(deg, rowptr, bsum);
    scan_bsum_kernel<<<1, 64, 0, stream>>>(bsum, NSCAN);
    finalize_rowptr_kernel<<<cdiv(N_NODES, BLK), BLK, 0, stream>>>(rowptr, bsum, cursor);
    scatter_kernel<<<cdiv(E2_EDGES, BLK), BLK, 0, stream>>>(ei, cursor, csr_src);

    // ===================== Layer 1 (F_IN -> H*C) =====================
    mfma_lin_pipe_kernel<F_IN, HC, 64, true><<<cdiv(N_NODES, 32), 256, 0, stream>>>(
        xh, xl, wt1h, wt1l, nullptr, bufH, N_NODES);
    attn_logits_kernel<HEADS, CH><<<cdiv((long long)N_NODES * HEADS, BLK), BLK, 0, stream>>>(
        bufH, as1, ad1, als, ald, N_NODES);
    gat_agg_wide_kernel<<<cdiv(N_NODES, 4), 256, 0, stream>>>(
        csr_src, rowptr, deg, bufH, als, ald, b1, aggh, aggl, N_NODES);

    // ===================== Layer 2 (H*C -> H*C) =====================
    mfma_lin_pipe_kernel<HC, HC, 64, true><<<cdiv(N_NODES, 32), 256, 0, stream>>>(
        aggh, aggl, wt2h, wt2l, nullptr, bufH, N_NODES);
    attn_logits_kernel<HEADS, CH><<<cdiv((long long)N_NODES * HEADS, BLK), BLK, 0, stream>>>(
        bufH, as2, ad2, als, ald, N_NODES);
    gat_agg_wide_kernel<<<cdiv(N_NODES, 4), 256, 0, stream>>>(
        csr_src, rowptr, deg, bufH, als, ald, b2, aggh, aggl, N_NODES);

    // ===================== Layer 3 (H*C -> C, heads=1) =====================
    mfma_lin_pipe_kernel<HC, CH, 64, true><<<cdiv(N_NODES, 128), 256, 0, stream>>>(
        aggh, aggl, wt3h, wt3l, nullptr, bufH, N_NODES);
    attn_logits_kernel<1, CH><<<cdiv(N_NODES, BLK), BLK, 0, stream>>>(
        bufH, as3, ad3, als, ald, N_NODES);
    gat_agg_h1_kernel<<<cdiv(N_NODES, 4), 256, 0, stream>>>(
        csr_src, rowptr, deg, bufH, als, ald, b3, bufO3, N_NODES);

    // ===================== Mean pooling (batch is sorted) =====================
    pool_kernel<<<NB, 64, 0, stream>>>(bufO3, batch, xg);

    // ===================== MLP head + LayerNorm =====================
    lin_kernel<CH, NHID, 16, 256, true><<<cdiv(NB, 16), 256, 0, stream>>>(
        xg, Wm1, bm1, y1, NB);
    mlp2_ln_kernel<<<NB, 256, 0, stream>>>(y1, Wm2, bm2, g2, be2, out);
}

// Round 10
// 433.651 us; speedup vs baseline: 1.2016x; 1.0894x over previous
//
#include <hip/hip_runtime.h>
#include <hip/hip_bf16.h>

#define N_NODES 50000
#define N_EDGES 500000
#define E2_EDGES 550000   // with self loops appended
#define F_IN 32
#define HEADS 4
#define CH 64
#define HC 256            // HEADS*CH
#define NB 1000
#define NHID 256
#define NOUT 256

static inline int cdiv(long long a, long long b) { return (int)((a + b - 1) / b); }

typedef __bf16 bf16x8 __attribute__((ext_vector_type(8)));
typedef unsigned short us8 __attribute__((ext_vector_type(8)));
typedef unsigned short us4 __attribute__((ext_vector_type(4)));
typedef float f32x4 __attribute__((ext_vector_type(4)));
union BU { us8 u; bf16x8 b; };

// round-to-nearest-even fp32 -> bf16 (bit pattern)
__device__ inline unsigned short f2bf(float f) {
    unsigned u = __float_as_uint(f);
    return (unsigned short)((u + 0x7fffu + ((u >> 16) & 1u)) >> 16);
}
__device__ inline float bf2f(unsigned short h) {
    return __uint_as_float(((unsigned)h) << 16);
}

// ---------- split fp32 array -> (hi,lo) bf16 planes ----------
__global__ void split_kernel(const float* __restrict__ in,
                             unsigned short* __restrict__ oh,
                             unsigned short* __restrict__ ol, int n) {
    int i = blockIdx.x * blockDim.x + threadIdx.x;
    if (i >= n) return;
    float v = in[i];
    unsigned short hi = f2bf(v);
    oh[i] = hi;
    ol[i] = f2bf(v - bf2f(hi));
}

// ---------- W prep: split fp32 -> (hi,lo) bf16 in MFMA-fragment-major order --
// Wf[((tcol*NCH + ch)*64 + lane)*8 + j]: lane=quad*16+l16 holds
// W[ch*32+quad*8+j][tcol*16+l16]. Wave B-load = base + lane*16B (coalesced 1KB).
__global__ void wconv_frag_kernel(const float* __restrict__ W,
                                  unsigned short* __restrict__ Wf_hi,
                                  unsigned short* __restrict__ Wf_lo, int K, int M) {
    int idx = blockIdx.x * blockDim.x + threadIdx.x;
    if (idx >= K * M) return;
    int k = idx / M, m = idx % M;
    float v = W[idx];
    unsigned short hi = f2bf(v);
    unsigned short lo = f2bf(v - bf2f(hi));
    int tcol = m >> 4, l16 = m & 15;
    int ch = k >> 5, quad = (k >> 3) & 3, j = k & 7;
    int NCH = K >> 5;
    size_t dst = ((((size_t)tcol * NCH + ch) * 64) + quad * 16 + l16) * 8 + j;
    Wf_hi[dst] = hi;
    Wf_lo[dst] = lo;
}

// ====== fused split-bf16 MFMA GEMM + attention logits =======================
// C[N,M] = A[N,K] @ W[K,M], M = H*64. Wave = 64 rows x 64 cols (one head).
// 4 rowsets (acc=64 VGPR) -> 48 MFMA per 16 loads per chunk; for M=256 all
// 4 waves of a block share the same 64 A rows (dup loads hit L1).
// Epilogue stores bf16 h and computes als/ald (per-row dot with a_src/a_dst)
// via in-register partials + shfl_xor reduce over the 16 l16 lanes -> the
// separate attn_logits pass (3x 25MB re-read of h) is eliminated.
template<int K, int M>
__global__ __launch_bounds__(256) void mfma_lin_fused_kernel(
    const unsigned short* __restrict__ Ah, const unsigned short* __restrict__ Al,
    const unsigned short* __restrict__ Wf_hi, const unsigned short* __restrict__ Wf_lo,
    const float* __restrict__ a_src, const float* __restrict__ a_dst,
    unsigned short* __restrict__ Hout, float* __restrict__ als,
    float* __restrict__ ald, int n_rows) {
    constexpr int NCH = K / 32;     // K chunks
    constexpr int CW = M / 64;      // col waves per block (= heads covered)
    constexpr int RW = 4 / CW;      // row-wave groups per block
    constexpr int H_ = M / 64;      // heads
    const int wave = threadIdx.x >> 6, lane = threadIdx.x & 63;
    const int quad = lane >> 4, l16 = lane & 15;
    const int head = wave % CW;
    const int col0 = head * 64;
    const int row0 = blockIdx.x * (RW * 64) + (wave / CW) * 64;

    f32x4 acc[4][4];
#pragma unroll
    for (int rs = 0; rs < 4; rs++)
#pragma unroll
        for (int t = 0; t < 4; t++) acc[rs][t] = (f32x4){0.f, 0.f, 0.f, 0.f};

    const unsigned short* aph[4];
    const unsigned short* apl[4];
#pragma unroll
    for (int rs = 0; rs < 4; rs++) {
        int r = min(row0 + rs * 16 + l16, n_rows - 1);
        aph[rs] = Ah + (size_t)r * K + quad * 8;
        apl[rs] = Al + (size_t)r * K + quad * 8;
    }
    const unsigned short* bh = Wf_hi + ((size_t)(col0 >> 4) * NCH * 64 + lane) * 8;
    const unsigned short* bl = Wf_lo + ((size_t)(col0 >> 4) * NCH * 64 + lane) * 8;

#pragma unroll
    for (int ch = 0; ch < NCH; ch++) {
        BU a_h[4], a_l[4], b_h[4], b_l[4];
#pragma unroll
        for (int rs = 0; rs < 4; rs++) {
            a_h[rs].u = *(const us8*)(aph[rs] + ch * 32);
            a_l[rs].u = *(const us8*)(apl[rs] + ch * 32);
        }
#pragma unroll
        for (int t = 0; t < 4; t++) {
            b_h[t].u = *(const us8*)(bh + (size_t)(t * NCH + ch) * 512);
            b_l[t].u = *(const us8*)(bl + (size_t)(t * NCH + ch) * 512);
        }
#pragma unroll
        for (int t = 0; t < 4; t++) {
#pragma unroll
            for (int rs = 0; rs < 4; rs++) {
                acc[rs][t] = __builtin_amdgcn_mfma_f32_16x16x32_bf16(a_h[rs].b, b_h[t].b, acc[rs][t], 0, 0, 0);
                acc[rs][t] = __builtin_amdgcn_mfma_f32_16x16x32_bf16(a_h[rs].b, b_l[t].b, acc[rs][t], 0, 0, 0);
                acc[rs][t] = __builtin_amdgcn_mfma_f32_16x16x32_bf16(a_l[rs].b, b_h[t].b, acc[rs][t], 0, 0, 0);
            }
        }
    }

    // ---- epilogue: store h (bf16) + fused attention logits ----
    float sv[4], dv[4];
#pragma unroll
    for (int t = 0; t < 4; t++) {
        sv[t] = a_src[col0 + t * 16 + l16];
        dv[t] = a_dst[col0 + t * 16 + l16];
    }
#pragma unroll
    for (int rs = 0; rs < 4; rs++) {
        const int orow0 = row0 + rs * 16 + quad * 4;
#pragma unroll
        for (int i = 0; i < 4; i++) {
            int r = orow0 + i;
            bool ok = (r < n_rows);
            float ps = 0.f, pd = 0.f;
#pragma unroll
            for (int t = 0; t < 4; t++) {
                float v = acc[rs][t][i];
                ps += v * sv[t];
                pd += v * dv[t];
                if (ok) Hout[(size_t)r * M + col0 + t * 16 + l16] = f2bf(v);
            }
            ps += __shfl_xor(ps, 1);  pd += __shfl_xor(pd, 1);
            ps += __shfl_xor(ps, 2);  pd += __shfl_xor(pd, 2);
            ps += __shfl_xor(ps, 4);  pd += __shfl_xor(pd, 4);
            ps += __shfl_xor(ps, 8);  pd += __shfl_xor(pd, 8);
            if (l16 == 0 && ok) {
                als[r * H_ + head] = ps;
                ald[r * H_ + head] = pd;
            }
        }
    }
}

// ---------- generic small GEMM (MLP layer 1) ----------
template<int K, int M, int TM, int BLOCK, bool RELU>
__global__ __launch_bounds__(BLOCK) void lin_kernel(
    const float* __restrict__ A, const float* __restrict__ W,
    const float* __restrict__ bias, float* __restrict__ C, int n_rows) {
    __shared__ float As[TM][K];
    const int n0 = blockIdx.x * TM;
    const int tid = threadIdx.x;
    for (int idx = tid; idx < TM * K; idx += BLOCK) {
        int r = idx / K, c = idx % K;
        int n = n0 + r;
        As[r][c] = (n < n_rows) ? A[(size_t)n * K + c] : 0.f;
    }
    __syncthreads();
    constexpr int G = BLOCK / M;
    constexpr int RPT = TM / G;
    const int j = tid % M;
    const int g = tid / M;
    float acc[RPT];
#pragma unroll
    for (int i = 0; i < RPT; i++) acc[i] = 0.f;
    for (int k = 0; k < K; k++) {
        float wk = W[(size_t)k * M + j];
#pragma unroll
        for (int i = 0; i < RPT; i++) acc[i] += As[g * RPT + i][k] * wk;
    }
    float bv = bias ? bias[j] : 0.f;
#pragma unroll
    for (int i = 0; i < RPT; i++) {
        int n = n0 + g * RPT + i;
        if (n < n_rows) {
            float v = acc[i] + bv;
            if (RELU) v = fmaxf(v, 0.f);
            C[(size_t)n * M + j] = v;
        }
    }
}

// ======================= CSR build =======================
__global__ void hist_kernel(const int* __restrict__ ei, int* __restrict__ deg) {
    int e = blockIdx.x * blockDim.x + threadIdx.x;
    if (e >= E2_EDGES) return;
    int d = (e < N_EDGES) ? ei[N_EDGES + e] : (e - N_EDGES);
    atomicAdd(deg + d, 1);
}

__global__ __launch_bounds__(256) void scan_block_kernel(const int* __restrict__ deg,
                                                         int* __restrict__ rowptr,
                                                         int* __restrict__ bsum) {
    __shared__ int sdata[256];
    const int b = blockIdx.x, t = threadIdx.x;
    const int base = b * 1024 + t * 4;
    int v[4]; int s = 0;
#pragma unroll
    for (int i = 0; i < 4; i++) {
        int idx = base + i;
        v[i] = (idx < N_NODES) ? deg[idx] : 0;
        s += v[i];
    }
    sdata[t] = s;
    __syncthreads();
    for (int o = 1; o < 256; o <<= 1) {
        int x = (t >= o) ? sdata[t - o] : 0;
        __syncthreads();
        sdata[t] += x;
        __syncthreads();
    }
    if (t == 255) bsum[b] = sdata[255];
    int run = sdata[t] - s;
#pragma unroll
    for (int i = 0; i < 4; i++) {
        int idx = base + i;
        if (idx < N_NODES) rowptr[idx] = run;
        run += v[i];
    }
}

__global__ void scan_bsum_kernel(int* __restrict__ bsum, int nb) {
    if (threadIdx.x == 0 && blockIdx.x == 0) {
        int run = 0;
        for (int i = 0; i < nb; i++) { int v = bsum[i]; bsum[i] = run; run += v; }
    }
}

__global__ void finalize_rowptr_kernel(int* __restrict__ rowptr, const int* __restrict__ bsum,
                                       int* __restrict__ cursor) {
    int i = blockIdx.x * blockDim.x + threadIdx.x;
    if (i >= N_NODES) return;
    int v = rowptr[i] + bsum[i >> 10];
    rowptr[i] = v;
    cursor[i] = v;
}

__global__ void scatter_kernel(const int* __restrict__ ei, int* __restrict__ cursor,
                               int* __restrict__ csr_src) {
    int e = blockIdx.x * blockDim.x + threadIdx.x;
    if (e >= E2_EDGES) return;
    int s, d;
    if (e < N_EDGES) { s = ei[e]; d = ei[N_EDGES + e]; }
    else             { s = d = e - N_EDGES; }
    int pos = atomicAdd(cursor + d, 1);
    csr_src[pos] = s;
}

// ===== wide GAT agg: 1 wave/node, lane owns 4 ch; writes hi/lo bf16 planes ===
__global__ __launch_bounds__(256) void gat_agg_wide_kernel(
    const int* __restrict__ csr_src, const int* __restrict__ rowptr,
    const int* __restrict__ deg, const unsigned short* __restrict__ h,
    const float* __restrict__ als, const float* __restrict__ ald,
    const float* __restrict__ bias, unsigned short* __restrict__ outh,
    unsigned short* __restrict__ outl, int n) {
    const int lane = threadIdx.x & 63;
    const int node = (blockIdx.x << 2) + (threadIdx.x >> 6);
    if (node >= n) return;
    const int hh = lane >> 4;
    const int start = rowptr[node];
    const int len = deg[node];
    const float ad = ald[(node << 2) + hh];
    float m = -1e30f, z = 0.f;
    float4 acc = make_float4(0.f, 0.f, 0.f, 0.f);
    int k = 0;
    for (; k + 4 <= len; k += 4) {
        int s0 = csr_src[start + k + 0];
        int s1 = csr_src[start + k + 1];
        int s2 = csr_src[start + k + 2];
        int s3 = csr_src[start + k + 3];
        float a0 = als[(s0 << 2) + hh], a1 = als[(s1 << 2) + hh];
        float a2 = als[(s2 << 2) + hh], a3 = als[(s3 << 2) + hh];
        us4 h0 = *(const us4*)(h + ((size_t)s0 << 8) + (lane << 2));
        us4 h1 = *(const us4*)(h + ((size_t)s1 << 8) + (lane << 2));
        us4 h2 = *(const us4*)(h + ((size_t)s2 << 8) + (lane << 2));
        us4 h3 = *(const us4*)(h + ((size_t)s3 << 8) + (lane << 2));
        float x0 = a0 + ad; x0 = (x0 > 0.f) ? x0 : 0.2f * x0;
        float x1 = a1 + ad; x1 = (x1 > 0.f) ? x1 : 0.2f * x1;
        float x2 = a2 + ad; x2 = (x2 > 0.f) ? x2 : 0.2f * x2;
        float x3 = a3 + ad; x3 = (x3 > 0.f) ? x3 : 0.2f * x3;
        float nm = fmaxf(fmaxf(fmaxf(x0, x1), fmaxf(x2, x3)), m);
        float c  = __expf(m - nm);
        float p0 = __expf(x0 - nm), p1 = __expf(x1 - nm);
        float p2 = __expf(x2 - nm), p3 = __expf(x3 - nm);
        m = nm;
        z = z * c + p0 + p1 + p2 + p3;
        acc.x = acc.x * c + p0 * bf2f(h0[0]) + p1 * bf2f(h1[0]) + p2 * bf2f(h2[0]) + p3 * bf2f(h3[0]);
        acc.y = acc.y * c + p0 * bf2f(h0[1]) + p1 * bf2f(h1[1]) + p2 * bf2f(h2[1]) + p3 * bf2f(h3[1]);
        acc.z = acc.z * c + p0 * bf2f(h0[2]) + p1 * bf2f(h1[2]) + p2 * bf2f(h2[2]) + p3 * bf2f(h3[2]);
        acc.w = acc.w * c + p0 * bf2f(h0[3]) + p1 * bf2f(h1[3]) + p2 * bf2f(h2[3]) + p3 * bf2f(h3[3]);
    }
    for (; k < len; k++) {
        int s0 = csr_src[start + k];
        float x0 = als[(s0 << 2) + hh] + ad; x0 = (x0 > 0.f) ? x0 : 0.2f * x0;
        us4 h0 = *(const us4*)(h + ((size_t)s0 << 8) + (lane << 2));
        float nm = fmaxf(m, x0);
        float c  = __expf(m - nm);
        float p0 = __expf(x0 - nm);
        m = nm;
        z = z * c + p0;
        acc.x = acc.x * c + p0 * bf2f(h0[0]);
        acc.y = acc.y * c + p0 * bf2f(h0[1]);
        acc.z = acc.z * c + p0 * bf2f(h0[2]);
        acc.w = acc.w * c + p0 * bf2f(h0[3]);
    }
    float inv = 1.f / (z + 1e-16f);
    float4 bv = *(const float4*)(bias + (lane << 2));
    float v[4];
    v[0] = fmaxf(acc.x * inv + bv.x, 0.f);   // relu=true for layers 1,2
    v[1] = fmaxf(acc.y * inv + bv.y, 0.f);
    v[2] = fmaxf(acc.z * inv + bv.z, 0.f);
    v[3] = fmaxf(acc.w * inv + bv.w, 0.f);
    us4 vh, vl;
#pragma unroll
    for (int i = 0; i < 4; i++) {
        unsigned short hi = f2bf(v[i]);
        vh[i] = hi;
        vl[i] = f2bf(v[i] - bf2f(hi));
    }
    *(us4*)(outh + ((size_t)node << 8) + (lane << 2)) = vh;
    *(us4*)(outl + ((size_t)node << 8) + (lane << 2)) = vl;
}

// ======================= layer-3 agg: H=1, C=64 (bf16 h, fp32 out) ======
__global__ __launch_bounds__(256) void gat_agg_h1_kernel(
    const int* __restrict__ csr_src, const int* __restrict__ rowptr,
    const int* __restrict__ deg, const unsigned short* __restrict__ h,
    const float* __restrict__ als, const float* __restrict__ ald,
    const float* __restrict__ bias, float* __restrict__ out, int n) {
    const int lane = threadIdx.x & 63;
    const int node = (blockIdx.x << 2) + (threadIdx.x >> 6);
    if (node >= n) return;
    const int start = rowptr[node];
    const int len = deg[node];
    const float ad = ald[node];
    float m = -1e30f, z = 0.f, acc = 0.f;
    int k = 0;
    for (; k + 4 <= len; k += 4) {
        int s0 = csr_src[start + k + 0];
        int s1 = csr_src[start + k + 1];
        int s2 = csr_src[start + k + 2];
        int s3 = csr_src[start + k + 3];
        float a0 = als[s0], a1 = als[s1], a2 = als[s2], a3 = als[s3];
        float h0 = bf2f(h[((size_t)s0 << 6) + lane]);
        float h1 = bf2f(h[((size_t)s1 << 6) + lane]);
        float h2 = bf2f(h[((size_t)s2 << 6) + lane]);
        float h3 = bf2f(h[((size_t)s3 << 6) + lane]);
        float x0 = a0 + ad; x0 = (x0 > 0.f) ? x0 : 0.2f * x0;
        float x1 = a1 + ad; x1 = (x1 > 0.f) ? x1 : 0.2f * x1;
        float x2 = a2 + ad; x2 = (x2 > 0.f) ? x2 : 0.2f * x2;
        float x3 = a3 + ad; x3 = (x3 > 0.f) ? x3 : 0.2f * x3;
        float nm = fmaxf(fmaxf(fmaxf(x0, x1), fmaxf(x2, x3)), m);
        float c  = __expf(m - nm);
        float p0 = __expf(x0 - nm), p1 = __expf(x1 - nm);
        float p2 = __expf(x2 - nm), p3 = __expf(x3 - nm);
        m = nm;
        z = z * c + p0 + p1 + p2 + p3;
        acc = acc * c + p0 * h0 + p1 * h1 + p2 * h2 + p3 * h3;
    }
    for (; k < len; k++) {
        int s0 = csr_src[start + k];
        float x0 = als[s0] + ad; x0 = (x0 > 0.f) ? x0 : 0.2f * x0;
        float h0 = bf2f(h[((size_t)s0 << 6) + lane]);
        float nm = fmaxf(m, x0);
        float c  = __expf(m - nm);
        float p0 = __expf(x0 - nm);
        m = nm;
        z = z * c + p0;
        acc = acc * c + p0 * h0;
    }
    out[((size_t)node << 6) + lane] = acc / (z + 1e-16f) + bias[lane];
}

// ---------- mean pooling over (sorted) batch via binary search ----------
__global__ __launch_bounds__(64) void pool_kernel(const float* __restrict__ h3,
                                                  const int* __restrict__ batch,
                                                  float* __restrict__ xg) {
    const int b = blockIdx.x;
    const int j = threadIdx.x;
    int lo = 0, hi = N_NODES;
    while (lo < hi) { int mid = (lo + hi) >> 1; if (batch[mid] < b) lo = mid + 1; else hi = mid; }
    const int start = lo;
    hi = N_NODES;
    while (lo < hi) { int mid = (lo + hi) >> 1; if (batch[mid] < b + 1) lo = mid + 1; else hi = mid; }
    const int end = lo;
    float s = 0.f;
    for (int n = start; n < end; n++) s += h3[(size_t)n * CH + j];
    xg[b * CH + j] = s / fmaxf((float)(end - start), 1.f);
}

// ---------- MLP layer 2 + LayerNorm, one block per graph ----------
__global__ __launch_bounds__(256) void mlp2_ln_kernel(
    const float* __restrict__ y1, const float* __restrict__ Wm2,
    const float* __restrict__ bm2, const float* __restrict__ g2,
    const float* __restrict__ be2, float* __restrict__ out) {
    const int b = blockIdx.x;
    const int j = threadIdx.x;
    __shared__ float yr[NHID];
    yr[j] = y1[(size_t)b * NHID + j];
    __syncthreads();
    float acc = bm2[j];
#pragma unroll 8
    for (int k = 0; k < NHID; k++) acc += yr[k] * Wm2[(size_t)k * NOUT + j];
    float s = acc, s2 = acc * acc;
    for (int o = 32; o > 0; o >>= 1) {
        s += __shfl_down(s, o);
        s2 += __shfl_down(s2, o);
    }
    __shared__ float red[8];
    __shared__ float mv[2];
    int wave = j >> 6, lane = j & 63;
    if (lane == 0) { red[wave] = s; red[4 + wave] = s2; }
    __syncthreads();
    if (j == 0) {
        float ts = red[0] + red[1] + red[2] + red[3];
        float ts2 = red[4] + red[5] + red[6] + red[7];
        float mu = ts / (float)NOUT;
        float var = ts2 / (float)NOUT - mu * mu;
        mv[0] = mu;
        mv[1] = rsqrtf(var + 1e-5f);
    }
    __syncthreads();
    out[(size_t)b * NOUT + j] = (acc - mv[0]) * mv[1] * g2[j] + be2[j];
}

extern "C" void kernel_launch(void* const* d_in, const int* in_sizes, int n_in,
                              void* d_out, int out_size, void* d_ws, size_t ws_size,
                              hipStream_t stream) {
    const float* x      = (const float*)d_in[0];
    const int*   ei     = (const int*)d_in[1];
    const int*   batch  = (const int*)d_in[2];
    const float* W1     = (const float*)d_in[3];
    const float* as1    = (const float*)d_in[4];
    const float* ad1    = (const float*)d_in[5];
    const float* b1     = (const float*)d_in[6];
    const float* W2     = (const float*)d_in[7];
    const float* as2    = (const float*)d_in[8];
    const float* ad2    = (const float*)d_in[9];
    const float* b2     = (const float*)d_in[10];
    const float* W3     = (const float*)d_in[11];
    const float* as3    = (const float*)d_in[12];
    const float* ad3    = (const float*)d_in[13];
    const float* b3     = (const float*)d_in[14];
    const float* Wm1    = (const float*)d_in[15];
    const float* bm1    = (const float*)d_in[16];
    const float* Wm2    = (const float*)d_in[17];
    const float* bm2    = (const float*)d_in[18];
    const float* g2     = (const float*)d_in[19];
    const float* be2    = (const float*)d_in[20];
    float* out = (float*)d_out;

    // workspace layout
    unsigned short* bufH = (unsigned short*)d_ws;                  // N*HC bf16 (GEMM out)
    unsigned short* aggh = bufH + (size_t)N_NODES * HC;            // N*HC
    unsigned short* aggl = aggh + (size_t)N_NODES * HC;            // N*HC
    unsigned short* xh   = aggl + (size_t)N_NODES * HC;            // N*F_IN
    unsigned short* xl   = xh + (size_t)N_NODES * F_IN;            // N*F_IN
    float* bufO3 = (float*)(xl + (size_t)N_NODES * F_IN);          // N*CH fp32
    float* als   = bufO3 + (size_t)N_NODES * CH;                   // N*HEADS
    float* ald   = als + (size_t)N_NODES * HEADS;                  // N*HEADS
    float* xg    = ald + (size_t)N_NODES * HEADS;                  // NB*CH
    float* y1    = xg + (size_t)NB * CH;                           // NB*NHID
    int* deg     = (int*)(y1 + (size_t)NB * NHID);                 // N
    int* rowptr  = deg + N_NODES;                                  // N
    int* cursor  = rowptr + N_NODES;                               // N
    int* bsum    = cursor + N_NODES;                               // <=64
    int* csr_src = bsum + 64;                                      // E2
    unsigned short* wt1h = (unsigned short*)(csr_src + E2_EDGES);  // 256*32
    unsigned short* wt1l = wt1h + 256 * 32;
    unsigned short* wt2h = wt1l + 256 * 32;                        // 256*256
    unsigned short* wt2l = wt2h + 256 * 256;
    unsigned short* wt3h = wt2l + 256 * 256;                       // 64*256
    unsigned short* wt3l = wt3h + 64 * 256;

    const int BLK = 256;
    const int NSCAN = cdiv(N_NODES, 1024);

    // ===================== weight + input prep ==============================
    wconv_frag_kernel<<<cdiv(F_IN * HC, BLK), BLK, 0, stream>>>(W1, wt1h, wt1l, F_IN, HC);
    wconv_frag_kernel<<<cdiv(HC * HC, BLK), BLK, 0, stream>>>(W2, wt2h, wt2l, HC, HC);
    wconv_frag_kernel<<<cdiv(HC * CH, BLK), BLK, 0, stream>>>(W3, wt3h, wt3l, HC, CH);
    split_kernel<<<cdiv(N_NODES * F_IN, BLK), BLK, 0, stream>>>(x, xh, xl, N_NODES * F_IN);

    // ===================== CSR build (dst-sorted adjacency) ==================
    hipMemsetAsync(deg, 0, (size_t)N_NODES * sizeof(int), stream);
    hist_kernel<<<cdiv(E2_EDGES, BLK), BLK, 0, stream>>>(ei, deg);
    scan_block_kernel<<<NSCAN, 256, 0, stream>>>(deg, rowptr, bsum);
    scan_bsum_kernel<<<1, 64, 0, stream>>>(bsum, NSCAN);
    finalize_rowptr_kernel<<<cdiv(N_NODES, BLK), BLK, 0, stream>>>(rowptr, bsum, cursor);
    scatter_kernel<<<cdiv(E2_EDGES, BLK), BLK, 0, stream>>>(ei, cursor, csr_src);

    // ===================== Layer 1 (F_IN -> H*C) =====================
    mfma_lin_fused_kernel<F_IN, HC><<<cdiv(N_NODES, 64), 256, 0, stream>>>(
        xh, xl, wt1h, wt1l, as1, ad1, bufH, als, ald, N_NODES);
    gat_agg_wide_kernel<<<cdiv(N_NODES, 4), 256, 0, stream>>>(
        csr_src, rowptr, deg, bufH, als, ald, b1, aggh, aggl, N_NODES);

    // ===================== Layer 2 (H*C -> H*C) =====================
    mfma_lin_fused_kernel<HC, HC><<<cdiv(N_NODES, 64), 256, 0, stream>>>(
        aggh, aggl, wt2h, wt2l, as2, ad2, bufH, als, ald, N_NODES);
    gat_agg_wide_kernel<<<cdiv(N_NODES, 4), 256, 0, stream>>>(
        csr_src, rowptr, deg, bufH, als, ald, b2, aggh, aggl, N_NODES);

    // ===================== Layer 3 (H*C -> C, heads=1) =====================
    mfma_lin_fused_kernel<HC, CH><<<cdiv(N_NODES, 256), 256, 0, stream>>>(
        aggh, aggl, wt3h, wt3l, as3, ad3, bufH, als, ald, N_NODES);
    gat_agg_h1_kernel<<<cdiv(N_NODES, 4), 256, 0, stream>>>(
        csr_src, rowptr, deg, bufH, als, ald, b3, bufO3, N_NODES);

    // ===================== Mean pooling (batch is sorted) =====================
    pool_kernel<<<NB, 64, 0, stream>>>(bufO3, batch, xg);

    // ===================== MLP head + LayerNorm =====================
    lin_kernel<CH, NHID, 16, 256, true><<<cdiv(NB, 16), 256, 0, stream>>>(
        xg, Wm1, bm1, y1, NB);
    mlp2_ln_kernel<<<NB, 256, 0, stream>>>(y1, Wm2, bm2, g2, be2, out);
}